// Round 3
// baseline (460.054 us; speedup 1.0000x reference)
//
#include <hip/hip_runtime.h>
#include <hip/hip_bf16.h>
#include <math.h>

#define NB 8
#define NT 1024
#define ND 768
#define NH 12
#define HD 64
#define WINDOW 768
#define LN_EPS 1e-5f
#define NEGF -3.4028234663852886e38f
#define SCL2 0.18033688011112042f   // 0.125 * log2(e)

static const int BT = NB * NT;  // 8192 rows

typedef __bf16 bf16x8 __attribute__((ext_vector_type(8)));
typedef float  f32x4  __attribute__((ext_vector_type(4)));
typedef unsigned short ushort_t;

__device__ __forceinline__ unsigned short f2bf(float f) {
    __hip_bfloat16 h = __float2bfloat16(f);
    return __builtin_bit_cast(unsigned short, h);
}

// async global->LDS, 16B per lane. LDS dest = wave-uniform base + lane*16.
__device__ __forceinline__ void load_lds16(const void* g, void* l) {
    __builtin_amdgcn_global_load_lds((const __attribute__((address_space(1))) unsigned int*)g,
                                     (__attribute__((address_space(3))) unsigned int*)l,
                                     16, 0, 0);
}

// inline-asm ds_read_b128: invisible to the compiler's waitcnt legalizer; caller
// manages lgkmcnt explicitly (counted waits, rule-18 sched_barrier discipline).
__device__ __forceinline__ bf16x8 ds_read16(const ushort_t* p) {
    bf16x8 r;
    unsigned a = (unsigned)(size_t)(const __attribute__((address_space(3))) ushort_t*)p;
    asm volatile("ds_read_b128 %0, %1" : "=v"(r) : "v"(a));
    return r;
}

// ---------------- all weight transposes fused: wT[n][k] = bf16(w[k][n]) --------
__global__ __launch_bounds__(256) void transpose_all(const float* __restrict__ w0, ushort_t* __restrict__ t0v,
                                                     const float* __restrict__ w1, ushort_t* __restrict__ t1v,
                                                     const float* __restrict__ w2, ushort_t* __restrict__ t2v,
                                                     const float* __restrict__ w3, ushort_t* __restrict__ t3v) {
    int bid = blockIdx.x;
    const float* w; ushort_t* wt; int K, N;
    if (bid < 1728)                    { w = w0; wt = t0v; K = 768;  N = 2304; }
    else if ((bid -= 1728) < 576)      { w = w1; wt = t1v; K = 768;  N = 768;  }
    else if ((bid -= 576) < 2304)      { w = w2; wt = t2v; K = 768;  N = 3072; }
    else       { bid -= 2304;            w = w3; wt = t3v; K = 3072; N = 768;  }
    const int nxt = N / 32;
    const int n0 = (bid % nxt) * 32, k0 = (bid / nxt) * 32;
    __shared__ float t[32][33];
    const int tx = threadIdx.x & 31, ty = threadIdx.x >> 5;  // 32 x 8
    for (int r = ty; r < 32; r += 8)
        t[r][tx] = w[(size_t)(k0 + r) * N + n0 + tx];
    __syncthreads();
    for (int r = ty; r < 32; r += 8)
        wt[(size_t)(n0 + r) * K + k0 + tx] = f2bf(t[tx][r]);
}

// ---------------- V transpose (pi-permuted keys): vT[b][h][d][t'] --------------
__global__ __launch_bounds__(256) void transpose_v(const ushort_t* __restrict__ qkvb,
                                                   ushort_t* __restrict__ vT) {
    const int t0 = blockIdx.x * 64;
    const int h = blockIdx.y, b = blockIdx.z;
    __shared__ ushort_t sm[64 * 72];
    const int tid = threadIdx.x;
    #pragma unroll
    for (int p = 0; p < 2; p++) {
        int idx = p * 256 + tid;
        int r = idx >> 3, c = idx & 7;
        *(bf16x8*)&sm[r * 72 + c * 8] =
            *(const bf16x8*)(qkvb + (size_t)(b * NT + t0 + r) * (3 * ND) + 2 * ND + h * HD + c * 8);
    }
    __syncthreads();
    #pragma unroll
    for (int p = 0; p < 2; p++) {
        int idx = p * 256 + tid;
        int d = idx >> 3, c2 = idx & 7;
        ushort_t tmp[8];
        #pragma unroll
        for (int j = 0; j < 8; j++) {
            int kp = c2 * 8 + j;
            int key = ((kp & 1) << 4) | ((kp >> 1) & 15) | (kp & 32);
            tmp[j] = sm[key * 72 + d];
        }
        *(bf16x8*)(vT + ((size_t)((b * NH + h) * HD + d)) * NT + t0 + c2 * 8) = *(bf16x8*)tmp;
    }
}

// ---------------- LayerNorm -> bf16: wave-per-row, shuffle reduce --------------
__global__ __launch_bounds__(256) void ln_kernel(const float* __restrict__ x,
                                                 const float* __restrict__ w,
                                                 const float* __restrict__ b,
                                                 ushort_t* __restrict__ out) {
    const int row  = blockIdx.x * 4 + (threadIdx.x >> 6);
    const int lane = threadIdx.x & 63;
    const float* xr = x + (size_t)row * ND;

    float4 v[3];
    #pragma unroll
    for (int s = 0; s < 3; s++) v[s] = *(const float4*)(xr + s * 256 + lane * 4);

    float sum = 0.f;
    #pragma unroll
    for (int s = 0; s < 3; s++) sum += v[s].x + v[s].y + v[s].z + v[s].w;
    #pragma unroll
    for (int off = 1; off < 64; off <<= 1) sum += __shfl_xor(sum, off, 64);
    const float mu = sum * (1.0f / ND);

    float var = 0.f;
    #pragma unroll
    for (int s = 0; s < 3; s++) {
        float a0 = v[s].x - mu, a1 = v[s].y - mu, a2 = v[s].z - mu, a3 = v[s].w - mu;
        var += a0 * a0 + a1 * a1 + a2 * a2 + a3 * a3;
    }
    #pragma unroll
    for (int off = 1; off < 64; off <<= 1) var += __shfl_xor(var, off, 64);
    const float rstd = rsqrtf(var * (1.0f / ND) + LN_EPS);

    #pragma unroll
    for (int s = 0; s < 3; s++) {
        const int col = s * 256 + lane * 4;
        float4 w4 = *(const float4*)(w + col);
        float4 b4 = *(const float4*)(b + col);
        ushort4 r;
        r.x = f2bf((v[s].x - mu) * rstd * w4.x + b4.x);
        r.y = f2bf((v[s].y - mu) * rstd * w4.y + b4.y);
        r.z = f2bf((v[s].z - mu) * rstd * w4.z + b4.z);
        r.w = f2bf((v[s].w - mu) * rstd * w4.w + b4.w);
        *(ushort4*)(out + (size_t)row * ND + col) = r;
    }
}

// ---------------- bf16 MFMA GEMM, double-buffered pipeline (128x128) -----------
// Kept for the two N=768 GEMMs (256-tile kernel would leave most CUs idle there).
// EPI: 1 = +bias+resid -> fp32
template <int EPI>
__global__ __launch_bounds__(256) void gemm_bt(const ushort_t* __restrict__ A,
                                               const ushort_t* __restrict__ Bt,
                                               const float* __restrict__ bias,
                                               const float* __restrict__ resid,
                                               void* __restrict__ Cout,
                                               int M, int N, int K) {
    __shared__ __align__(16) ushort_t smem[2][2][128 * 32];  // [buf][A/B][...]

    const int tid  = threadIdx.x;
    const int bm   = blockIdx.y * 128;
    const int bn   = blockIdx.x * 128;
    const int lane = tid & 63;
    const int wave = tid >> 6;
    const int wm   = (wave & 1) * 64;
    const int wn   = (wave >> 1) * 64;
    const int fcol = lane & 15;
    const int quad = lane >> 4;

    f32x4 acc[4][4] = {};

    const int srow = tid >> 2, scg = (tid & 3) * 8;

    auto issue = [&](int k0, int buf) {
        #pragma unroll
        for (int p = 0; p < 2; p++) {
            const int row = srow + p * 64;
            const int flat = (p * 256 + tid) * 8;
            load_lds16(A  + (size_t)(bm + row) * K + k0 + scg, &smem[buf][0][flat]);
            load_lds16(Bt + (size_t)(bn + row) * K + k0 + scg, &smem[buf][1][flat]);
        }
    };

    issue(0, 0);
    const int KT = K >> 5;
    for (int kt = 0; kt < KT; kt++) {
        const int cur = kt & 1;
        __syncthreads();
        if (kt + 1 < KT) issue((kt + 1) << 5, cur ^ 1);

        bf16x8 a[4], b[4];
        #pragma unroll
        for (int i = 0; i < 4; i++)
            a[i] = *(const bf16x8*)&smem[cur][0][(wm + i * 16 + fcol) * 32 + quad * 8];
        #pragma unroll
        for (int j = 0; j < 4; j++)
            b[j] = *(const bf16x8*)&smem[cur][1][(wn + j * 16 + fcol) * 32 + quad * 8];
        #pragma unroll
        for (int i = 0; i < 4; i++)
            #pragma unroll
            for (int j = 0; j < 4; j++)
                acc[i][j] = __builtin_amdgcn_mfma_f32_16x16x32_bf16(a[i], b[j], acc[i][j], 0, 0, 0);
    }

    if (EPI == 1) {
        #pragma unroll
        for (int j = 0; j < 4; j++) {
            const int gcol = bn + wn + j * 16 + fcol;
            const float bs = bias[gcol];
            #pragma unroll
            for (int i = 0; i < 4; i++) {
                #pragma unroll
                for (int r = 0; r < 4; r++) {
                    const int grow = bm + wm + i * 16 + quad * 4 + r;
                    float val = acc[i][j][r] + bs + resid[(size_t)grow * N + gcol];
                    ((float*)Cout)[(size_t)grow * N + gcol] = val;
                }
            }
        }
    } else {
        __syncthreads();
        ushort_t* Cs = &smem[0][0][0] + wave * (64 * 40);
        #pragma unroll
        for (int hh = 0; hh < 2; hh++) {
            #pragma unroll
            for (int jj = 0; jj < 2; jj++) {
                const int j = hh * 2 + jj;
                const float bs = bias[bn + wn + j * 16 + fcol];
                #pragma unroll
                for (int i = 0; i < 4; i++) {
                    #pragma unroll
                    for (int r = 0; r < 4; r++) {
                        float val = acc[i][j][r] + bs;
                        if (EPI == 2) {
                            float y = 0.7978845608028654f * (val + 0.044715f * val * val * val);
                            float t = 1.0f - 2.0f / (1.0f + __expf(2.0f * y));
                            val = 0.5f * val * (1.0f + t);
                        }
                        const int lr = i * 16 + quad * 4 + r;
                        Cs[lr * 40 + jj * 16 + fcol] = f2bf(val);
                    }
                }
            }
            #pragma unroll
            for (int p = 0; p < 4; p++) {
                const int cid = p * 64 + lane;
                const int lr = cid >> 2, ck = cid & 3;
                bf16x8 vv = *(const bf16x8*)&Cs[lr * 40 + ck * 8];
                *(bf16x8*)((ushort_t*)Cout + (size_t)(bm + wm + lr) * N + bn + wn + hh * 32 + ck * 8) = vv;
            }
        }
    }
}

// ---------------- 256x256 8-phase GEMM, pipelined fragment reads ---------------
// Geometry + stage ledger identical to round 1/2 (verified correct). New: fragment
// ds_reads issue ONE PHASE EARLY and are drained with COUNTED lgkmcnt(N) (N = reads
// just issued), so the previous phase's reads hide under a full MFMA cluster.
//   reg plan: raA = A mh0, raB = A mh1 (fixed roles; reload >=2 phases after last
//   use). B: rb[2] buffers, role alternates per tile (tile t: nh0@buf t&1).
//   waits: P1:lgkm(4) P2:lgkm(8) P3:lgkm(0) P4:none (+VMW6, then 12-read lookahead
//   for P5 — must be post-VMW6 since its A(O,mh0)/B(O,nh0) slots land exactly
//   there); P5..P8 mirror. One inline-asm s_barrier per phase; VMW6 precedes the
//   barrier => landing is published block-wide before any dependent read issues
//   (the P4/P8 lookaheads rely on own-wave VMW6 + >=5-barrier staging distance).
// EPI: 0 = +bias -> bf16;  2 = +bias,gelu(tanh) -> bf16
template <int EPI, int NN, int KK>
__global__ __launch_bounds__(512, 2) void gemm256(const ushort_t* __restrict__ A,
                                                  const ushort_t* __restrict__ Bt,
                                                  const float* __restrict__ bias,
                                                  ushort_t* __restrict__ Cout) {
    extern __shared__ __align__(16) ushort_t lds[];

    const int tid  = threadIdx.x;
    const int lane = tid & 63;
    const int wave = tid >> 6;     // 0..7
    const int wr   = wave >> 2;    // 0..1  (M half)
    const int wn   = wave & 3;     // 0..3  (N quarter)
    const int fcol = lane & 15;
    const int quad = lane >> 4;

    // XCD-aware chunked swizzle (nwg % 8 == 0 for both instantiations).
    const int nwg   = gridDim.x * gridDim.y;
    const int flatb = blockIdx.y * gridDim.x + blockIdx.x;
    const int q8    = nwg >> 3;
    const int swz   = (flatb & 7) * q8 + (flatb >> 3);
    const int bm    = (swz / gridDim.x) * 256;
    const int bn    = (swz % gridDim.x) * 256;

    constexpr int KT  = KK >> 6;   // 64-wide K tiles
    constexpr int NIT = KT >> 1;   // double-tile iterations

    f32x4 acc[8][4] = {};
    bf16x8 raA[4][2], raB[4][2];   // A mh0 / mh1 fragments (32+32 VGPR)
    bf16x8 rb[2][2][2];            // [buf][j2][ks] B buffers (32 VGPR)

    ushort_t* const Ab = lds;           // 4 slots x 8192 ushorts
    ushort_t* const Bb = lds + 32768;   // 4 slots x 8192 ushorts

    auto stA = [&](int kt, int h) {
        ushort_t* dst = Ab + ((((kt & 1) << 1) | h) << 13);
        const int kk = (kt < KT ? kt : 0) << 6;   // dummy tail stages keep vmcnt ledger
        #pragma unroll
        for (int p = 0; p < 2; p++) {
            const int f = (p << 9) + tid;
            const int r = f >> 3, c = (f & 7) ^ (r & 7);
            const int gr = bm + ((r >> 6) << 7) + (h << 6) + (r & 63);
            load_lds16(A + (size_t)gr * KK + kk + c * 8, dst + f * 8);
        }
    };
    auto stB = [&](int kt, int h) {
        ushort_t* dst = Bb + ((((kt & 1) << 1) | h) << 13);
        const int kk = (kt < KT ? kt : 0) << 6;
        #pragma unroll
        for (int p = 0; p < 2; p++) {
            const int f = (p << 9) + tid;
            const int r = f >> 3, c = (f & 7) ^ (r & 7);
            const int gr = bn + ((r >> 5) << 6) + (h << 5) + (r & 31);
            load_lds16(Bt + (size_t)gr * KK + kk + c * 8, dst + f * 8);
        }
    };

#define SOFF(r, c) ((((r) << 3) + (((c) ^ ((r) & 7)))) << 3)
#define RD_A(PAR, MH, RA) { const ushort_t* s_ = Ab + ((((PAR) << 1) | (MH)) << 13);  \
    _Pragma("unroll") for (int i2 = 0; i2 < 4; i2++)                                  \
    _Pragma("unroll") for (int ks = 0; ks < 2; ks++)                                  \
        RA[i2][ks] = ds_read16(&s_[SOFF(wr * 64 + i2 * 16 + fcol, ks * 4 + quad)]); }
#define RD_B(PAR, NH, BUF) { const ushort_t* s_ = Bb + ((((PAR) << 1) | (NH)) << 13); \
    _Pragma("unroll") for (int j2 = 0; j2 < 2; j2++)                                  \
    _Pragma("unroll") for (int ks = 0; ks < 2; ks++)                                  \
        rb[BUF][j2][ks] = ds_read16(&s_[SOFF(wn * 32 + j2 * 16 + fcol, ks * 4 + quad)]); }
#define LGKM(N) { asm volatile("s_waitcnt lgkmcnt(" #N ")" ::: "memory");             \
    __builtin_amdgcn_sched_barrier(0); }
#define MMA_CORE(MH, NH, BUF) {                                                       \
    __builtin_amdgcn_sched_barrier(0);                                                \
    __builtin_amdgcn_s_setprio(1);                                                    \
    _Pragma("unroll") for (int i2 = 0; i2 < 4; i2++)                                  \
    _Pragma("unroll") for (int j2 = 0; j2 < 2; j2++)                                  \
    _Pragma("unroll") for (int ks = 0; ks < 2; ks++)                                  \
        acc[(MH) * 4 + i2][(NH) * 2 + j2] = __builtin_amdgcn_mfma_f32_16x16x32_bf16(  \
            (MH) ? raB[i2][ks] : raA[i2][ks], rb[BUF][j2][ks],                        \
            acc[(MH) * 4 + i2][(NH) * 2 + j2], 0, 0, 0);                              \
    __builtin_amdgcn_s_setprio(0);                                                    \
    __builtin_amdgcn_sched_barrier(0); }
#define VMW6() asm volatile("s_waitcnt vmcnt(6)" ::: "memory")
#define BARR() asm volatile("s_barrier" ::: "memory")

    // prologue: tile0 (4 halves), tile1 {A-mh0, B-nh0, B-nh1}; then preload P1 frags
    stA(0, 0); stB(0, 0); stB(0, 1); stA(0, 1);
    stA(1, 0); stB(1, 0); stB(1, 1);
    VMW6();                                   // tile0 (8 oldest loads) fully landed
    BARR();
    RD_A(0, 0, raA);                          // A(t0,mh0)
    RD_B(0, 0, 0);                            // B(t0,nh0) -> buf0

    #pragma unroll 1
    for (int it = 0; it < NIT; ++it) {
        const int E = it << 1, O = E + 1;
        // ---- tile E (par0; nh0@buf0, nh1@buf1) ----
        RD_B(0, 1, 1);            // B(E,nh1)
        stA(O, 1);
        LGKM(4);                  // P1 frags (12 issued last phase) done
        MMA_CORE(0, 0, 0);
        BARR();

        RD_A(0, 1, raB);          // A(E,mh1)
        stA(E + 2, 0);
        LGKM(8);                  // B(E,nh1) done
        MMA_CORE(0, 1, 1);
        BARR();

        stB(E + 2, 0);
        LGKM(0);                  // A(E,mh1) done
        MMA_CORE(1, 1, 1);
        BARR();

        MMA_CORE(1, 0, 0);        // operands already drained
        stB(E + 2, 1);
        VMW6();                   // tile-O slots landed (own-wave)
        RD_A(1, 0, raA);          // A(O,mh0)
        RD_B(1, 0, 1);            // B(O,nh0) -> buf1
        BARR();

        // ---- tile O (par1; nh0@buf1, nh1@buf0) ----
        RD_B(1, 1, 0);            // B(O,nh1)
        stA(E + 2, 1);
        LGKM(4);
        MMA_CORE(0, 0, 1);
        BARR();

        RD_A(1, 1, raB);          // A(O,mh1)
        stA(O + 2, 0);
        LGKM(8);
        MMA_CORE(0, 1, 0);
        BARR();

        stB(O + 2, 0);
        LGKM(0);
        MMA_CORE(1, 1, 0);
        BARR();

        MMA_CORE(1, 0, 1);
        stB(O + 2, 1);
        VMW6();
        RD_A(0, 0, raA);          // A(E+2,mh0) (dummy-read on final iter, regs dead)
        RD_B(0, 0, 0);            // B(E+2,nh0) -> buf0
        BARR();
    }

    // drain everything before reusing LDS for the C epilogue
    asm volatile("s_waitcnt vmcnt(0) lgkmcnt(0)" ::: "memory");
    BARR();

    // epilogue: per-wave-private LDS staging (64 rows x 64 cols per m-half, pad 72)
    ushort_t* Cs = lds + wave * (64 * 72);
    #pragma unroll
    for (int h = 0; h < 2; h++) {
        #pragma unroll
        for (int j = 0; j < 4; j++) {
            const float bs = bias[bn + wn * 64 + j * 16 + fcol];
            #pragma unroll
            for (int i2 = 0; i2 < 4; i2++) {
                #pragma unroll
                for (int r = 0; r < 4; r++) {
                    float val = acc[h * 4 + i2][j][r] + bs;
                    if (EPI == 2) {
                        float y = 0.7978845608028654f * (val + 0.044715f * val * val * val);
                        float t = 1.0f - 2.0f / (1.0f + __expf(2.0f * y));
                        val = 0.5f * val * (1.0f + t);
                    }
                    Cs[(i2 * 16 + quad * 4 + r) * 72 + j * 16 + fcol] = f2bf(val);
                }
            }
        }
        #pragma unroll
        for (int p = 0; p < 8; p++) {
            const int cid = (p << 6) + lane;
            const int lr = cid >> 3, ck = cid & 7;
            bf16x8 vv = *(const bf16x8*)&Cs[lr * 72 + ck * 8];
            *(bf16x8*)(Cout + (size_t)(bm + wr * 128 + h * 64 + lr) * NN + bn + wn * 64 + ck * 8) = vv;
        }
    }
#undef SOFF
#undef RD_A
#undef RD_B
#undef LGKM
#undef MMA_CORE
#undef VMW6
#undef BARR
}

// ---------------- MFMA flash attention: no-max softmax, l via ones-MFMA --------
__global__ __launch_bounds__(256) void flash_attn_mfma(const ushort_t* __restrict__ qkvb,
                                                       const ushort_t* __restrict__ vT,
                                                       const int* __restrict__ amask,
                                                       ushort_t* __restrict__ out) {
    const int qt = 15 - blockIdx.x;   // heavy tiles first
    const int h  = blockIdx.y;
    const int b  = blockIdx.z;
    const int q0 = qt * 64;

    __shared__ __align__(16) ushort_t QPs[64 * 64];      // Q, then reused for P
    __shared__ __align__(16) ushort_t Ks[2][64 * 64];
    __shared__ __align__(16) ushort_t Vts[2][64 * 64];

    const int tid  = threadIdx.x;
    const int lane = tid & 63;
    const int wave = tid >> 6;
    const int fcol = lane & 15;
    const int quad = lane >> 4;
    const int wq0  = wave * 16;

    #pragma unroll
    for (int p = 0; p < 2; p++) {
        int flat = p * 256 + tid;
        int r = flat >> 3, c = (flat & 7) ^ (r & 7);
        load_lds16(qkvb + (size_t)(b * NT + q0 + r) * (3 * ND) + h * HD + c * 8, &QPs[flat * 8]);
    }
    __syncthreads();

    bf16x8 aQ[2];
    {
        const int qr = wq0 + fcol;
        #pragma unroll
        for (int ks = 0; ks < 2; ks++) {
            int c = ks * 4 + quad;
            aQ[ks] = *(const bf16x8*)&QPs[qr * 64 + ((c ^ (qr & 7)) * 8)];
        }
    }

    bf16x8 bones;
    #pragma unroll
    for (int i = 0; i < 8; i++) bones[i] = (__bf16)1.0f;

    auto issueKV = [&](int cch, int buf) {
        const int kbase = cch * 64;
        #pragma unroll
        for (int p = 0; p < 2; p++) {
            int flat = p * 256 + tid;
            int r = flat >> 3, c = (flat & 7) ^ (r & 7);
            load_lds16(qkvb + (size_t)(b * NT + kbase + r) * (3 * ND) + ND + h * HD + c * 8,
                       &Ks[buf][flat * 8]);
            load_lds16(vT + ((size_t)((b * NH + h) * HD + r)) * NT + kbase + c * 8,
                       &Vts[buf][flat * 8]);
        }
    };

    f32x4 oacc[4] = {};
    f32x4 lacc = {};

    const int c_lo = (qt > 12) ? (qt - 12) : 0;
    issueKV(c_lo, 0);
    for (int cch = c_lo; cch <= qt; cch++) {
        const int cur = (cch - c_lo) & 1;
        const int kbase = cch * 64;
        __syncthreads();
        if (cch + 1 <= qt) issueKV(cch + 1, cur ^ 1);

        int am[4];
        #pragma unroll
        for (int jn = 0; jn < 4; jn++) am[jn] = amask[b * NT + kbase + jn * 16 + fcol];
        const int amok_lane = (am[0] != 0) & (am[1] != 0) & (am[2] != 0) & (am[3] != 0);
        const bool fast = (cch < qt) && (cch >= qt - 11) && __all(amok_lane);

        f32x4 sc[4] = {};
        #pragma unroll
        for (int ks = 0; ks < 2; ks++) {
            #pragma unroll
            for (int jn = 0; jn < 4; jn++) {
                const int kr = jn * 16 + fcol;
                bf16x8 bk = *(const bf16x8*)&Ks[cur][kr * 64 + (((ks * 4 + quad) ^ (kr & 7)) * 8)];
                sc[jn] = __builtin_amdgcn_mfma_f32_16x16x32_bf16(aQ[ks], bk, sc[jn], 0, 0, 0);
            }
        }

        float pvv[4][4];
        if (fast) {
            #pragma unroll
            for (int jn = 0; jn < 4; jn++)
                #pragma unroll
                for (int r = 0; r < 4; r++)
                    pvv[jn][r] = __builtin_amdgcn_exp2f(sc[jn][r] * SCL2);
        } else {
            #pragma unroll
            for (int jn = 0; jn < 4; jn++) {
                const int jg = kbase + jn * 16 + fcol;
                const bool amok = (am[jn] != 0);
                #pragma unroll
                for (int r = 0; r < 4; r++) {
                    const int ig = q0 + wq0 + quad * 4 + r;
                    bool keep = (jg <= ig) && (jg >= ig - (WINDOW - 1)) && amok;
                    float s = keep ? sc[jn][r] * SCL2 : -1e38f;
                    pvv[jn][r] = __builtin_amdgcn_exp2f(s);
                }
            }
        }

        #pragma unroll
        for (int half = 0; half < 2; half++) {
            const int cbase = half * 4 + (fcol >> 2);
            const int off = (fcol & 3) * 2;
            #pragma unroll
            for (int r = 0; r < 4; r++) {
                const int row = wq0 + quad * 4 + r;
                unsigned int pk = (unsigned int)f2bf(pvv[half * 2][r]) |
                                  ((unsigned int)f2bf(pvv[half * 2 + 1][r]) << 16);
                *(unsigned int*)&QPs[row * 64 + ((cbase ^ (row & 7)) * 8) + off] = pk;
            }
        }

        #pragma unroll
        for (int ks = 0; ks < 2; ks++) {
            const int pr = wq0 + fcol;
            bf16x8 ap = *(const bf16x8*)&QPs[pr * 64 + (((ks * 4 + quad) ^ (pr & 7)) * 8)];
            lacc = __builtin_amdgcn_mfma_f32_16x16x32_bf16(ap, bones, lacc, 0, 0, 0);
            #pragma unroll
            for (int jd = 0; jd < 4; jd++) {
                const int vr = jd * 16 + fcol;
                bf16x8 bv = *(const bf16x8*)&Vts[cur][vr * 64 + (((ks * 4 + quad) ^ (vr & 7)) * 8)];
                oacc[jd] = __builtin_amdgcn_mfma_f32_16x16x32_bf16(ap, bv, oacc[jd], 0, 0, 0);
            }
        }
    }

    #pragma unroll
    for (int r = 0; r < 4; r++) {
        const float inv = 1.0f / lacc[r];
        const size_t row = (size_t)(b * NT + q0 + wq0 + quad * 4 + r);
        #pragma unroll
        for (int jd = 0; jd < 4; jd++)
            out[row * ND + h * HD + jd * 16 + fcol] = f2bf(oacc[jd][r] * inv);
    }
}

extern "C" void kernel_launch(void* const* d_in, const int* in_sizes, int n_in,
                              void* d_out, int out_size, void* d_ws, size_t ws_size,
                              hipStream_t stream) {
    const float* x        = (const float*)d_in[0];
    const int*   amask    = (const int*)  d_in[1];
    const float* ln1_w    = (const float*)d_in[2];
    const float* ln1_b    = (const float*)d_in[3];
    const float* w_attn   = (const float*)d_in[4];
    const float* b_attn   = (const float*)d_in[5];
    const float* w_proj   = (const float*)d_in[6];
    const float* b_proj   = (const float*)d_in[7];
    const float* ln2_w    = (const float*)d_in[8];
    const float* ln2_b    = (const float*)d_in[9];
    const float* w_fc     = (const float*)d_in[10];
    const float* b_fc     = (const float*)d_in[11];
    const float* w_fcp    = (const float*)d_in[12];
    const float* b_fcp    = (const float*)d_in[13];
    float* out = (float*)d_out;

    ushort_t* ws = (ushort_t*)d_ws;
    ushort_t* qkvb   = ws;                               // BT*3*ND
    ushort_t* x1b    = qkvb + (size_t)BT * 3 * ND;       // BT*ND
    ushort_t* attn_b = x1b + (size_t)BT * ND;            // BT*ND
    ushort_t* hbuf   = attn_b + (size_t)BT * ND;         // BT*4*ND
    ushort_t* vTb    = hbuf + (size_t)BT * 4 * ND;       // BT*ND
    ushort_t* wA_T   = vTb + (size_t)BT * ND;            // 2304*768
    ushort_t* wP_T   = wA_T + (size_t)2304 * 768;        // 768*768
    ushort_t* wF_T   = wP_T + (size_t)768 * 768;         // 3072*768
    ushort_t* wFP_T  = wF_T + (size_t)3072 * 768;        // 768*3072

    static bool attr_set = false;
    if (!attr_set) {
        hipFuncSetAttribute((const void*)gemm256<0, 2304, 768>, hipFuncAttributeMaxDynamicSharedMemorySize, 131072);
        hipFuncSetAttribute((const void*)gemm256<2, 3072, 768>, hipFuncAttributeMaxDynamicSharedMemorySize, 131072);
        attr_set = true;
    }

    transpose_all<<<6912, 256, 0, stream>>>(w_attn, wA_T, w_proj, wP_T, w_fc, wF_T, w_fcp, wFP_T);

    ln_kernel<<<BT / 4, 256, 0, stream>>>(x, ln1_w, ln1_b, x1b);
    gemm256<0, 2304, 768><<<dim3(2304 / 256, BT / 256), 512, 131072, stream>>>(x1b, wA_T, b_attn, qkvb);
    transpose_v<<<dim3(16, NH, NB), 256, 0, stream>>>(qkvb, vTb);
    flash_attn_mfma<<<dim3(16, NH, NB), 256, 0, stream>>>(qkvb, vTb, amask, attn_b);
    gemm_bt<1><<<dim3(768 / 128, BT / 128), 256, 0, stream>>>(attn_b, wP_T, b_proj, x, out, BT, ND, ND);
    ln_kernel<<<BT / 4, 256, 0, stream>>>(out, ln2_w, ln2_b, x1b);
    gemm256<2, 3072, 768><<<dim3(3072 / 256, BT / 256), 512, 131072, stream>>>(x1b, wF_T, b_fc, hbuf);
    gemm_bt<1><<<dim3(768 / 128, BT / 128), 256, 0, stream>>>(hbuf, wFP_T, b_fcp, out, out, BT, ND, 4 * ND);
}

// Round 4
// 400.950 us; speedup vs baseline: 1.1474x; 1.1474x over previous
//
#include <hip/hip_runtime.h>
#include <hip/hip_bf16.h>
#include <math.h>

#define NB 8
#define NT 1024
#define ND 768
#define NH 12
#define HD 64
#define WINDOW 768
#define LN_EPS 1e-5f
#define NEGF -3.4028234663852886e38f
#define SCL2 0.18033688011112042f   // 0.125 * log2(e)

static const int BT = NB * NT;  // 8192 rows

typedef __bf16 bf16x8 __attribute__((ext_vector_type(8)));
typedef float  f32x4  __attribute__((ext_vector_type(4)));
typedef unsigned short ushort_t;

__device__ __forceinline__ unsigned short f2bf(float f) {
    __hip_bfloat16 h = __float2bfloat16(f);
    return __builtin_bit_cast(unsigned short, h);
}

// async global->LDS, 16B per lane. LDS dest = wave-uniform base + lane*16.
__device__ __forceinline__ void load_lds16(const void* g, void* l) {
    __builtin_amdgcn_global_load_lds((const __attribute__((address_space(1))) unsigned int*)g,
                                     (__attribute__((address_space(3))) unsigned int*)l,
                                     16, 0, 0);
}

// inline-asm ds_read_b128 with compile-time offset immediate: ONE base VGPR serves
// all fragment reads of a class (slot + subtile folded into offset:IMM). This is
// the round-3 spill fix: 24 materialized address VGPRs -> 4 thread bases.
template <int IMM>
__device__ __forceinline__ bf16x8 ds_read16o(unsigned base) {
    bf16x8 r;
    asm volatile("ds_read_b128 %0, %1 offset:%2" : "=v"(r) : "v"(base), "n"(IMM));
    return r;
}

// ---------------- all weight transposes fused: wT[n][k] = bf16(w[k][n]) --------
__global__ __launch_bounds__(256) void transpose_all(const float* __restrict__ w0, ushort_t* __restrict__ t0v,
                                                     const float* __restrict__ w1, ushort_t* __restrict__ t1v,
                                                     const float* __restrict__ w2, ushort_t* __restrict__ t2v,
                                                     const float* __restrict__ w3, ushort_t* __restrict__ t3v) {
    int bid = blockIdx.x;
    const float* w; ushort_t* wt; int K, N;
    if (bid < 1728)                    { w = w0; wt = t0v; K = 768;  N = 2304; }
    else if ((bid -= 1728) < 576)      { w = w1; wt = t1v; K = 768;  N = 768;  }
    else if ((bid -= 576) < 2304)      { w = w2; wt = t2v; K = 768;  N = 3072; }
    else       { bid -= 2304;            w = w3; wt = t3v; K = 3072; N = 768;  }
    const int nxt = N / 32;
    const int n0 = (bid % nxt) * 32, k0 = (bid / nxt) * 32;
    __shared__ float t[32][33];
    const int tx = threadIdx.x & 31, ty = threadIdx.x >> 5;  // 32 x 8
    for (int r = ty; r < 32; r += 8)
        t[r][tx] = w[(size_t)(k0 + r) * N + n0 + tx];
    __syncthreads();
    for (int r = ty; r < 32; r += 8)
        wt[(size_t)(n0 + r) * K + k0 + tx] = f2bf(t[tx][r]);
}

// ---------------- V transpose (pi-permuted keys): vT[b][h][d][t'] --------------
__global__ __launch_bounds__(256) void transpose_v(const ushort_t* __restrict__ qkvb,
                                                   ushort_t* __restrict__ vT) {
    const int t0 = blockIdx.x * 64;
    const int h = blockIdx.y, b = blockIdx.z;
    __shared__ ushort_t sm[64 * 72];
    const int tid = threadIdx.x;
    #pragma unroll
    for (int p = 0; p < 2; p++) {
        int idx = p * 256 + tid;
        int r = idx >> 3, c = idx & 7;
        *(bf16x8*)&sm[r * 72 + c * 8] =
            *(const bf16x8*)(qkvb + (size_t)(b * NT + t0 + r) * (3 * ND) + 2 * ND + h * HD + c * 8);
    }
    __syncthreads();
    #pragma unroll
    for (int p = 0; p < 2; p++) {
        int idx = p * 256 + tid;
        int d = idx >> 3, c2 = idx & 7;
        ushort_t tmp[8];
        #pragma unroll
        for (int j = 0; j < 8; j++) {
            int kp = c2 * 8 + j;
            int key = ((kp & 1) << 4) | ((kp >> 1) & 15) | (kp & 32);
            tmp[j] = sm[key * 72 + d];
        }
        *(bf16x8*)(vT + ((size_t)((b * NH + h) * HD + d)) * NT + t0 + c2 * 8) = *(bf16x8*)tmp;
    }
}

// ---------------- LayerNorm -> bf16: wave-per-row, shuffle reduce --------------
__global__ __launch_bounds__(256) void ln_kernel(const float* __restrict__ x,
                                                 const float* __restrict__ w,
                                                 const float* __restrict__ b,
                                                 ushort_t* __restrict__ out) {
    const int row  = blockIdx.x * 4 + (threadIdx.x >> 6);
    const int lane = threadIdx.x & 63;
    const float* xr = x + (size_t)row * ND;

    float4 v[3];
    #pragma unroll
    for (int s = 0; s < 3; s++) v[s] = *(const float4*)(xr + s * 256 + lane * 4);

    float sum = 0.f;
    #pragma unroll
    for (int s = 0; s < 3; s++) sum += v[s].x + v[s].y + v[s].z + v[s].w;
    #pragma unroll
    for (int off = 1; off < 64; off <<= 1) sum += __shfl_xor(sum, off, 64);
    const float mu = sum * (1.0f / ND);

    float var = 0.f;
    #pragma unroll
    for (int s = 0; s < 3; s++) {
        float a0 = v[s].x - mu, a1 = v[s].y - mu, a2 = v[s].z - mu, a3 = v[s].w - mu;
        var += a0 * a0 + a1 * a1 + a2 * a2 + a3 * a3;
    }
    #pragma unroll
    for (int off = 1; off < 64; off <<= 1) var += __shfl_xor(var, off, 64);
    const float rstd = rsqrtf(var * (1.0f / ND) + LN_EPS);

    #pragma unroll
    for (int s = 0; s < 3; s++) {
        const int col = s * 256 + lane * 4;
        float4 w4 = *(const float4*)(w + col);
        float4 b4 = *(const float4*)(b + col);
        ushort4 r;
        r.x = f2bf((v[s].x - mu) * rstd * w4.x + b4.x);
        r.y = f2bf((v[s].y - mu) * rstd * w4.y + b4.y);
        r.z = f2bf((v[s].z - mu) * rstd * w4.z + b4.z);
        r.w = f2bf((v[s].w - mu) * rstd * w4.w + b4.w);
        *(ushort4*)(out + (size_t)row * ND + col) = r;
    }
}

// ---------------- bf16 MFMA GEMM, double-buffered pipeline (128x128) -----------
// Kept for the two N=768 GEMMs. Now with bijective XCD-chunk swizzle (T1; all
// gemm_bt grids here are 384 blocks, %8==0).
// EPI: 1 = +bias+resid -> fp32
template <int EPI>
__global__ __launch_bounds__(256) void gemm_bt(const ushort_t* __restrict__ A,
                                               const ushort_t* __restrict__ Bt,
                                               const float* __restrict__ bias,
                                               const float* __restrict__ resid,
                                               void* __restrict__ Cout,
                                               int M, int N, int K) {
    __shared__ __align__(16) ushort_t smem[2][2][128 * 32];  // [buf][A/B][...]

    const int tid  = threadIdx.x;
    const int nwg   = gridDim.x * gridDim.y;
    const int flatb = blockIdx.y * gridDim.x + blockIdx.x;
    const int q8    = nwg >> 3;
    const int swz   = (flatb & 7) * q8 + (flatb >> 3);
    const int bm   = (swz / gridDim.x) * 128;
    const int bn   = (swz % gridDim.x) * 128;
    const int lane = tid & 63;
    const int wave = tid >> 6;
    const int wm   = (wave & 1) * 64;
    const int wn   = (wave >> 1) * 64;
    const int fcol = lane & 15;
    const int quad = lane >> 4;

    f32x4 acc[4][4] = {};

    const int srow = tid >> 2, scg = (tid & 3) * 8;

    auto issue = [&](int k0, int buf) {
        #pragma unroll
        for (int p = 0; p < 2; p++) {
            const int row = srow + p * 64;
            const int flat = (p * 256 + tid) * 8;
            load_lds16(A  + (size_t)(bm + row) * K + k0 + scg, &smem[buf][0][flat]);
            load_lds16(Bt + (size_t)(bn + row) * K + k0 + scg, &smem[buf][1][flat]);
        }
    };

    issue(0, 0);
    const int KT = K >> 5;
    for (int kt = 0; kt < KT; kt++) {
        const int cur = kt & 1;
        __syncthreads();
        if (kt + 1 < KT) issue((kt + 1) << 5, cur ^ 1);

        bf16x8 a[4], b[4];
        #pragma unroll
        for (int i = 0; i < 4; i++)
            a[i] = *(const bf16x8*)&smem[cur][0][(wm + i * 16 + fcol) * 32 + quad * 8];
        #pragma unroll
        for (int j = 0; j < 4; j++)
            b[j] = *(const bf16x8*)&smem[cur][1][(wn + j * 16 + fcol) * 32 + quad * 8];
        #pragma unroll
        for (int i = 0; i < 4; i++)
            #pragma unroll
            for (int j = 0; j < 4; j++)
                acc[i][j] = __builtin_amdgcn_mfma_f32_16x16x32_bf16(a[i], b[j], acc[i][j], 0, 0, 0);
    }

    if (EPI == 1) {
        #pragma unroll
        for (int j = 0; j < 4; j++) {
            const int gcol = bn + wn + j * 16 + fcol;
            const float bs = bias[gcol];
            #pragma unroll
            for (int i = 0; i < 4; i++) {
                #pragma unroll
                for (int r = 0; r < 4; r++) {
                    const int grow = bm + wm + i * 16 + quad * 4 + r;
                    float val = acc[i][j][r] + bs + resid[(size_t)grow * N + gcol];
                    ((float*)Cout)[(size_t)grow * N + gcol] = val;
                }
            }
        }
    } else {
        __syncthreads();
        ushort_t* Cs = &smem[0][0][0] + wave * (64 * 40);
        #pragma unroll
        for (int hh = 0; hh < 2; hh++) {
            #pragma unroll
            for (int jj = 0; jj < 2; jj++) {
                const int j = hh * 2 + jj;
                const float bs = bias[bn + wn + j * 16 + fcol];
                #pragma unroll
                for (int i = 0; i < 4; i++) {
                    #pragma unroll
                    for (int r = 0; r < 4; r++) {
                        float val = acc[i][j][r] + bs;
                        if (EPI == 2) {
                            float y = 0.7978845608028654f * (val + 0.044715f * val * val * val);
                            float t = 1.0f - 2.0f / (1.0f + __expf(2.0f * y));
                            val = 0.5f * val * (1.0f + t);
                        }
                        const int lr = i * 16 + quad * 4 + r;
                        Cs[lr * 40 + jj * 16 + fcol] = f2bf(val);
                    }
                }
            }
            #pragma unroll
            for (int p = 0; p < 4; p++) {
                const int cid = p * 64 + lane;
                const int lr = cid >> 2, ck = cid & 3;
                bf16x8 vv = *(const bf16x8*)&Cs[lr * 40 + ck * 8];
                *(bf16x8*)((ushort_t*)Cout + (size_t)(bm + wm + lr) * N + bn + wn + hh * 32 + ck * 8) = vv;
            }
        }
    }
}

// ---------------- 256x256 8-phase GEMM, pipelined fragment reads ---------------
// Schedule/ledger identical to round 3 (functionally verified). New: all fragment
// ds_reads use offset-immediate form off 4 per-thread base VGPRs — removes the
// ~24 materialized address VGPRs that pushed round 3 over the 128-arch-VGPR cap
// into scratch spill (WRITE_SIZE 49->83 MB).
//   frag byte addr = base(A/B, ks) + slot*16384 + i2*2048   (all imm <= 55296)
//   waits: P1:lgkm(4) P2:lgkm(8) P3:lgkm(0) P4:none (+VMW6, 12-read lookahead).
// EPI: 0 = +bias -> bf16;  2 = +bias,gelu(tanh) -> bf16
template <int EPI, int NN, int KK>
__global__ __launch_bounds__(512, 2) void gemm256(const ushort_t* __restrict__ A,
                                                  const ushort_t* __restrict__ Bt,
                                                  const float* __restrict__ bias,
                                                  ushort_t* __restrict__ Cout) {
    extern __shared__ __align__(16) ushort_t lds[];

    const int tid  = threadIdx.x;
    const int lane = tid & 63;
    const int wave = tid >> 6;     // 0..7
    const int wr   = wave >> 2;    // 0..1  (M half)
    const int wn   = wave & 3;     // 0..3  (N quarter)
    const int fcol = lane & 15;
    const int quad = lane >> 4;

    // XCD-aware chunked swizzle (nwg % 8 == 0 for both instantiations).
    const int nwg   = gridDim.x * gridDim.y;
    const int flatb = blockIdx.y * gridDim.x + blockIdx.x;
    const int q8    = nwg >> 3;
    const int swz   = (flatb & 7) * q8 + (flatb >> 3);
    const int bm    = (swz / gridDim.x) * 256;
    const int bn    = (swz % gridDim.x) * 256;

    constexpr int KT  = KK >> 6;   // 64-wide K tiles
    constexpr int NIT = KT >> 1;   // double-tile iterations

    f32x4 acc[8][4] = {};
    bf16x8 raA[4][2], raB[4][2];   // A mh0 / mh1 fragments
    bf16x8 rb[2][2][2];            // [buf][j2][ks] B buffers

    ushort_t* const Ab = lds;           // 4 slots x 8192 ushorts
    ushort_t* const Bb = lds + 32768;   // 4 slots x 8192 ushorts

    // 4 fragment-read base addresses (all other addressing is offset: immediates)
    const unsigned f7 = (unsigned)(fcol & 7);
    const unsigned ldsA = (unsigned)(size_t)(const __attribute__((address_space(3))) ushort_t*)Ab;
    const unsigned ldsB = (unsigned)(size_t)(const __attribute__((address_space(3))) ushort_t*)Bb;
    unsigned baseA0 = ldsA + (unsigned)((wr * 64 + fcol) * 128 + ((quad) ^ f7) * 16);
    unsigned baseA1 = ldsA + (unsigned)((wr * 64 + fcol) * 128 + ((4 | quad) ^ f7) * 16);
    unsigned baseB0 = ldsB + (unsigned)((wn * 32 + fcol) * 128 + ((quad) ^ f7) * 16);
    unsigned baseB1 = ldsB + (unsigned)((wn * 32 + fcol) * 128 + ((4 | quad) ^ f7) * 16);

    auto stA = [&](int kt, int h) {
        ushort_t* dst = Ab + ((((kt & 1) << 1) | h) << 13);
        const int kk = (kt < KT ? kt : 0) << 6;   // dummy tail stages keep vmcnt ledger
        #pragma unroll
        for (int p = 0; p < 2; p++) {
            const int f = (p << 9) + tid;
            const int r = f >> 3, c = (f & 7) ^ (r & 7);
            const int gr = bm + ((r >> 6) << 7) + (h << 6) + (r & 63);
            load_lds16(A + (size_t)gr * KK + kk + c * 8, dst + f * 8);
        }
    };
    auto stB = [&](int kt, int h) {
        ushort_t* dst = Bb + ((((kt & 1) << 1) | h) << 13);
        const int kk = (kt < KT ? kt : 0) << 6;
        #pragma unroll
        for (int p = 0; p < 2; p++) {
            const int f = (p << 9) + tid;
            const int r = f >> 3, c = (f & 7) ^ (r & 7);
            const int gr = bn + ((r >> 5) << 6) + (h << 5) + (r & 31);
            load_lds16(Bt + (size_t)gr * KK + kk + c * 8, dst + f * 8);
        }
    };

// slot byte = ((PAR<<1)|S)*16384 ; subtile byte = I*2048 ; both compile-time.
#define RDA1(PAR, MH, RA, I2) {                                                       \
    RA[I2][0] = ds_read16o<((((PAR) << 1) | (MH)) * 16384 + (I2) * 2048)>(baseA0);    \
    RA[I2][1] = ds_read16o<((((PAR) << 1) | (MH)) * 16384 + (I2) * 2048)>(baseA1); }
#define RD_A(PAR, MH, RA) { RDA1(PAR, MH, RA, 0) RDA1(PAR, MH, RA, 1)                 \
                            RDA1(PAR, MH, RA, 2) RDA1(PAR, MH, RA, 3) }
#define RDB1(PAR, NH, BUF, J2) {                                                      \
    rb[BUF][J2][0] = ds_read16o<((((PAR) << 1) | (NH)) * 16384 + (J2) * 2048)>(baseB0);\
    rb[BUF][J2][1] = ds_read16o<((((PAR) << 1) | (NH)) * 16384 + (J2) * 2048)>(baseB1); }
#define RD_B(PAR, NH, BUF) { RDB1(PAR, NH, BUF, 0) RDB1(PAR, NH, BUF, 1) }
#define LGKM(N) { asm volatile("s_waitcnt lgkmcnt(" #N ")" ::: "memory");             \
    __builtin_amdgcn_sched_barrier(0); }
#define MMA_CORE(MH, NH, BUF) {                                                       \
    __builtin_amdgcn_sched_barrier(0);                                                \
    __builtin_amdgcn_s_setprio(1);                                                    \
    _Pragma("unroll") for (int i2 = 0; i2 < 4; i2++)                                  \
    _Pragma("unroll") for (int j2 = 0; j2 < 2; j2++)                                  \
    _Pragma("unroll") for (int ks = 0; ks < 2; ks++)                                  \
        acc[(MH) * 4 + i2][(NH) * 2 + j2] = __builtin_amdgcn_mfma_f32_16x16x32_bf16(  \
            (MH) ? raB[i2][ks] : raA[i2][ks], rb[BUF][j2][ks],                        \
            acc[(MH) * 4 + i2][(NH) * 2 + j2], 0, 0, 0);                              \
    __builtin_amdgcn_s_setprio(0);                                                    \
    __builtin_amdgcn_sched_barrier(0); }
#define VMW6() asm volatile("s_waitcnt vmcnt(6)" ::: "memory")
#define BARR() asm volatile("s_barrier" ::: "memory")

    // prologue: tile0 (4 halves), tile1 {A-mh0, B-nh0, B-nh1}; then preload P1 frags
    stA(0, 0); stB(0, 0); stB(0, 1); stA(0, 1);
    stA(1, 0); stB(1, 0); stB(1, 1);
    VMW6();                                   // tile0 (8 oldest loads) fully landed
    BARR();
    RD_A(0, 0, raA);                          // A(t0,mh0)
    RD_B(0, 0, 0);                            // B(t0,nh0) -> buf0

    #pragma unroll 1
    for (int it = 0; it < NIT; ++it) {
        const int E = it << 1, O = E + 1;
        // ---- tile E (par0; nh0@buf0, nh1@buf1) ----
        RD_B(0, 1, 1);            // B(E,nh1)
        stA(O, 1);
        LGKM(4);                  // P1 frags (12 issued last phase) done
        MMA_CORE(0, 0, 0);
        BARR();

        RD_A(0, 1, raB);          // A(E,mh1)
        stA(E + 2, 0);
        LGKM(8);                  // B(E,nh1) done
        MMA_CORE(0, 1, 1);
        BARR();

        stB(E + 2, 0);
        LGKM(0);                  // A(E,mh1) done
        MMA_CORE(1, 1, 1);
        BARR();

        MMA_CORE(1, 0, 0);        // operands already drained
        stB(E + 2, 1);
        VMW6();                   // tile-O slots landed (own-wave)
        RD_A(1, 0, raA);          // A(O,mh0)
        RD_B(1, 0, 1);            // B(O,nh0) -> buf1
        BARR();

        // ---- tile O (par1; nh0@buf1, nh1@buf0) ----
        RD_B(1, 1, 0);            // B(O,nh1)
        stA(E + 2, 1);
        LGKM(4);
        MMA_CORE(0, 0, 1);
        BARR();

        RD_A(1, 1, raB);          // A(O,mh1)
        stA(O + 2, 0);
        LGKM(8);
        MMA_CORE(0, 1, 0);
        BARR();

        stB(O + 2, 0);
        LGKM(0);
        MMA_CORE(1, 1, 0);
        BARR();

        MMA_CORE(1, 0, 1);
        stB(O + 2, 1);
        VMW6();
        RD_A(0, 0, raA);          // A(E+2,mh0) (dummy-read on final iter, regs dead)
        RD_B(0, 0, 0);            // B(E+2,nh0) -> buf0
        BARR();
    }

    // drain everything before reusing LDS for the C epilogue
    asm volatile("s_waitcnt vmcnt(0) lgkmcnt(0)" ::: "memory");
    BARR();

    // epilogue: per-wave-private LDS staging (64 rows x 64 cols per m-half, pad 72)
    ushort_t* Cs = lds + wave * (64 * 72);
    #pragma unroll
    for (int h = 0; h < 2; h++) {
        #pragma unroll
        for (int j = 0; j < 4; j++) {
            const float bs = bias[bn + wn * 64 + j * 16 + fcol];
            #pragma unroll
            for (int i2 = 0; i2 < 4; i2++) {
                #pragma unroll
                for (int r = 0; r < 4; r++) {
                    float val = acc[h * 4 + i2][j][r] + bs;
                    if (EPI == 2) {
                        float y = 0.7978845608028654f * (val + 0.044715f * val * val * val);
                        float t = 1.0f - 2.0f / (1.0f + __expf(2.0f * y));
                        val = 0.5f * val * (1.0f + t);
                    }
                    Cs[(i2 * 16 + quad * 4 + r) * 72 + j * 16 + fcol] = f2bf(val);
                }
            }
        }
        #pragma unroll
        for (int p = 0; p < 8; p++) {
            const int cid = (p << 6) + lane;
            const int lr = cid >> 3, ck = cid & 7;
            bf16x8 vv = *(const bf16x8*)&Cs[lr * 72 + ck * 8];
            *(bf16x8*)(Cout + (size_t)(bm + wr * 128 + h * 64 + lr) * NN + bn + wn * 64 + ck * 8) = vv;
        }
    }
#undef RDA1
#undef RD_A
#undef RDB1
#undef RD_B
#undef LGKM
#undef MMA_CORE
#undef VMW6
#undef BARR
}

// ---------------- MFMA flash attention: no-max softmax, l via ones-MFMA --------
__global__ __launch_bounds__(256) void flash_attn_mfma(const ushort_t* __restrict__ qkvb,
                                                       const ushort_t* __restrict__ vT,
                                                       const int* __restrict__ amask,
                                                       ushort_t* __restrict__ out) {
    const int qt = 15 - blockIdx.x;   // heavy tiles first
    const int h  = blockIdx.y;
    const int b  = blockIdx.z;
    const int q0 = qt * 64;

    __shared__ __align__(16) ushort_t QPs[64 * 64];      // Q, then reused for P
    __shared__ __align__(16) ushort_t Ks[2][64 * 64];
    __shared__ __align__(16) ushort_t Vts[2][64 * 64];

    const int tid  = threadIdx.x;
    const int lane = tid & 63;
    const int wave = tid >> 6;
    const int fcol = lane & 15;
    const int quad = lane >> 4;
    const int wq0  = wave * 16;

    #pragma unroll
    for (int p = 0; p < 2; p++) {
        int flat = p * 256 + tid;
        int r = flat >> 3, c = (flat & 7) ^ (r & 7);
        load_lds16(qkvb + (size_t)(b * NT + q0 + r) * (3 * ND) + h * HD + c * 8, &QPs[flat * 8]);
    }
    __syncthreads();

    bf16x8 aQ[2];
    {
        const int qr = wq0 + fcol;
        #pragma unroll
        for (int ks = 0; ks < 2; ks++) {
            int c = ks * 4 + quad;
            aQ[ks] = *(const bf16x8*)&QPs[qr * 64 + ((c ^ (qr & 7)) * 8)];
        }
    }

    bf16x8 bones;
    #pragma unroll
    for (int i = 0; i < 8; i++) bones[i] = (__bf16)1.0f;

    auto issueKV = [&](int cch, int buf) {
        const int kbase = cch * 64;
        #pragma unroll
        for (int p = 0; p < 2; p++) {
            int flat = p * 256 + tid;
            int r = flat >> 3, c = (flat & 7) ^ (r & 7);
            load_lds16(qkvb + (size_t)(b * NT + kbase + r) * (3 * ND) + ND + h * HD + c * 8,
                       &Ks[buf][flat * 8]);
            load_lds16(vT + ((size_t)((b * NH + h) * HD + r)) * NT + kbase + c * 8,
                       &Vts[buf][flat * 8]);
        }
    };

    f32x4 oacc[4] = {};
    f32x4 lacc = {};

    const int c_lo = (qt > 12) ? (qt - 12) : 0;
    issueKV(c_lo, 0);
    for (int cch = c_lo; cch <= qt; cch++) {
        const int cur = (cch - c_lo) & 1;
        const int kbase = cch * 64;
        __syncthreads();
        if (cch + 1 <= qt) issueKV(cch + 1, cur ^ 1);

        int am[4];
        #pragma unroll
        for (int jn = 0; jn < 4; jn++) am[jn] = amask[b * NT + kbase + jn * 16 + fcol];
        const int amok_lane = (am[0] != 0) & (am[1] != 0) & (am[2] != 0) & (am[3] != 0);
        const bool fast = (cch < qt) && (cch >= qt - 11) && __all(amok_lane);

        f32x4 sc[4] = {};
        #pragma unroll
        for (int ks = 0; ks < 2; ks++) {
            #pragma unroll
            for (int jn = 0; jn < 4; jn++) {
                const int kr = jn * 16 + fcol;
                bf16x8 bk = *(const bf16x8*)&Ks[cur][kr * 64 + (((ks * 4 + quad) ^ (kr & 7)) * 8)];
                sc[jn] = __builtin_amdgcn_mfma_f32_16x16x32_bf16(aQ[ks], bk, sc[jn], 0, 0, 0);
            }
        }

        float pvv[4][4];
        if (fast) {
            #pragma unroll
            for (int jn = 0; jn < 4; jn++)
                #pragma unroll
                for (int r = 0; r < 4; r++)
                    pvv[jn][r] = __builtin_amdgcn_exp2f(sc[jn][r] * SCL2);
        } else {
            #pragma unroll
            for (int jn = 0; jn < 4; jn++) {
                const int jg = kbase + jn * 16 + fcol;
                const bool amok = (am[jn] != 0);
                #pragma unroll
                for (int r = 0; r < 4; r++) {
                    const int ig = q0 + wq0 + quad * 4 + r;
                    bool keep = (jg <= ig) && (jg >= ig - (WINDOW - 1)) && amok;
                    float s = keep ? sc[jn][r] * SCL2 : -1e38f;
                    pvv[jn][r] = __builtin_amdgcn_exp2f(s);
                }
            }
        }

        #pragma unroll
        for (int half = 0; half < 2; half++) {
            const int cbase = half * 4 + (fcol >> 2);
            const int off = (fcol & 3) * 2;
            #pragma unroll
            for (int r = 0; r < 4; r++) {
                const int row = wq0 + quad * 4 + r;
                unsigned int pk = (unsigned int)f2bf(pvv[half * 2][r]) |
                                  ((unsigned int)f2bf(pvv[half * 2 + 1][r]) << 16);
                *(unsigned int*)&QPs[row * 64 + ((cbase ^ (row & 7)) * 8) + off] = pk;
            }
        }

        #pragma unroll
        for (int ks = 0; ks < 2; ks++) {
            const int pr = wq0 + fcol;
            bf16x8 ap = *(const bf16x8*)&QPs[pr * 64 + (((ks * 4 + quad) ^ (pr & 7)) * 8)];
            lacc = __builtin_amdgcn_mfma_f32_16x16x32_bf16(ap, bones, lacc, 0, 0, 0);
            #pragma unroll
            for (int jd = 0; jd < 4; jd++) {
                const int vr = jd * 16 + fcol;
                bf16x8 bv = *(const bf16x8*)&Vts[cur][vr * 64 + (((ks * 4 + quad) ^ (vr & 7)) * 8)];
                oacc[jd] = __builtin_amdgcn_mfma_f32_16x16x32_bf16(ap, bv, oacc[jd], 0, 0, 0);
            }
        }
    }

    #pragma unroll
    for (int r = 0; r < 4; r++) {
        const float inv = 1.0f / lacc[r];
        const size_t row = (size_t)(b * NT + q0 + wq0 + quad * 4 + r);
        #pragma unroll
        for (int jd = 0; jd < 4; jd++)
            out[row * ND + h * HD + jd * 16 + fcol] = f2bf(oacc[jd][r] * inv);
    }
}

extern "C" void kernel_launch(void* const* d_in, const int* in_sizes, int n_in,
                              void* d_out, int out_size, void* d_ws, size_t ws_size,
                              hipStream_t stream) {
    const float* x        = (const float*)d_in[0];
    const int*   amask    = (const int*)  d_in[1];
    const float* ln1_w    = (const float*)d_in[2];
    const float* ln1_b    = (const float*)d_in[3];
    const float* w_attn   = (const float*)d_in[4];
    const float* b_attn   = (const float*)d_in[5];
    const float* w_proj   = (const float*)d_in[6];
    const float* b_proj   = (const float*)d_in[7];
    const float* ln2_w    = (const float*)d_in[8];
    const float* ln2_b    = (const float*)d_in[9];
    const float* w_fc     = (const float*)d_in[10];
    const float* b_fc     = (const float*)d_in[11];
    const float* w_fcp    = (const float*)d_in[12];
    const float* b_fcp    = (const float*)d_in[13];
    float* out = (float*)d_out;

    ushort_t* ws = (ushort_t*)d_ws;
    ushort_t* qkvb   = ws;                               // BT*3*ND
    ushort_t* x1b    = qkvb + (size_t)BT * 3 * ND;       // BT*ND
    ushort_t* attn_b = x1b + (size_t)BT * ND;            // BT*ND
    ushort_t* hbuf   = attn_b + (size_t)BT * ND;         // BT*4*ND
    ushort_t* vTb    = hbuf + (size_t)BT * 4 * ND;       // BT*ND
    ushort_t* wA_T   = vTb + (size_t)BT * ND;            // 2304*768
    ushort_t* wP_T   = wA_T + (size_t)2304 * 768;        // 768*768
    ushort_t* wF_T   = wP_T + (size_t)768 * 768;         // 3072*768
    ushort_t* wFP_T  = wF_T + (size_t)3072 * 768;        // 768*3072

    static bool attr_set = false;
    if (!attr_set) {
        hipFuncSetAttribute((const void*)gemm256<0, 2304, 768>, hipFuncAttributeMaxDynamicSharedMemorySize, 131072);
        hipFuncSetAttribute((const void*)gemm256<2, 3072, 768>, hipFuncAttributeMaxDynamicSharedMemorySize, 131072);
        attr_set = true;
    }

    transpose_all<<<6912, 256, 0, stream>>>(w_attn, wA_T, w_proj, wP_T, w_fc, wF_T, w_fcp, wFP_T);

    ln_kernel<<<BT / 4, 256, 0, stream>>>(x, ln1_w, ln1_b, x1b);
    gemm256<0, 2304, 768><<<dim3(2304 / 256, BT / 256), 512, 131072, stream>>>(x1b, wA_T, b_attn, qkvb);
    transpose_v<<<dim3(16, NH, NB), 256, 0, stream>>>(qkvb, vTb);
    flash_attn_mfma<<<dim3(16, NH, NB), 256, 0, stream>>>(qkvb, vTb, amask, attn_b);
    gemm_bt<1><<<dim3(768 / 128, BT / 128), 256, 0, stream>>>(attn_b, wP_T, b_proj, x, out, BT, ND, ND);
    ln_kernel<<<BT / 4, 256, 0, stream>>>(out, ln2_w, ln2_b, x1b);
    gemm256<2, 3072, 768><<<dim3(3072 / 256, BT / 256), 512, 131072, stream>>>(x1b, wF_T, b_fc, hbuf);
    gemm_bt<1><<<dim3(768 / 128, BT / 128), 256, 0, stream>>>(hbuf, wFP_T, b_fcp, out, out, BT, ND, 4 * ND);
}

// Round 5
// 369.989 us; speedup vs baseline: 1.2434x; 1.0837x over previous
//
#include <hip/hip_runtime.h>
#include <hip/hip_bf16.h>
#include <math.h>

#define NB 8
#define NT 1024
#define ND 768
#define NH 12
#define HD 64
#define WINDOW 768
#define LN_EPS 1e-5f
#define NEGF -3.4028234663852886e38f
#define SCL2 0.18033688011112042f   // 0.125 * log2(e)

static const int BT = NB * NT;  // 8192 rows

typedef __bf16 bf16x8 __attribute__((ext_vector_type(8)));
typedef float  f32x4  __attribute__((ext_vector_type(4)));
typedef unsigned short ushort_t;

__device__ __forceinline__ unsigned short f2bf(float f) {
    __hip_bfloat16 h = __float2bfloat16(f);
    return __builtin_bit_cast(unsigned short, h);
}

// async global->LDS, 16B per lane. LDS dest = wave-uniform base + lane*16.
__device__ __forceinline__ void load_lds16(const void* g, void* l) {
    __builtin_amdgcn_global_load_lds((const __attribute__((address_space(1))) unsigned int*)g,
                                     (__attribute__((address_space(3))) unsigned int*)l,
                                     16, 0, 0);
}

// inline-asm ds_read_b128 with compile-time offset immediate: ONE base VGPR serves
// all fragment reads of a class (slot + subtile folded into offset:IMM).
template <int IMM>
__device__ __forceinline__ bf16x8 ds_read16o(unsigned base) {
    bf16x8 r;
    asm volatile("ds_read_b128 %0, %1 offset:%2" : "=v"(r) : "v"(base), "n"(IMM));
    return r;
}

// ---------------- all weight transposes fused: wT[n][k] = bf16(w[k][n]) --------
__global__ __launch_bounds__(256) void transpose_all(const float* __restrict__ w0, ushort_t* __restrict__ t0v,
                                                     const float* __restrict__ w1, ushort_t* __restrict__ t1v,
                                                     const float* __restrict__ w2, ushort_t* __restrict__ t2v,
                                                     const float* __restrict__ w3, ushort_t* __restrict__ t3v) {
    int bid = blockIdx.x;
    const float* w; ushort_t* wt; int K, N;
    if (bid < 1728)                    { w = w0; wt = t0v; K = 768;  N = 2304; }
    else if ((bid -= 1728) < 576)      { w = w1; wt = t1v; K = 768;  N = 768;  }
    else if ((bid -= 576) < 2304)      { w = w2; wt = t2v; K = 768;  N = 3072; }
    else       { bid -= 2304;            w = w3; wt = t3v; K = 3072; N = 768;  }
    const int nxt = N / 32;
    const int n0 = (bid % nxt) * 32, k0 = (bid / nxt) * 32;
    __shared__ float t[32][33];
    const int tx = threadIdx.x & 31, ty = threadIdx.x >> 5;  // 32 x 8
    for (int r = ty; r < 32; r += 8)
        t[r][tx] = w[(size_t)(k0 + r) * N + n0 + tx];
    __syncthreads();
    for (int r = ty; r < 32; r += 8)
        wt[(size_t)(n0 + r) * K + k0 + tx] = f2bf(t[tx][r]);
}

// ---------------- V transpose (pi-permuted keys): vT[b][h][d][t'] --------------
__global__ __launch_bounds__(256) void transpose_v(const ushort_t* __restrict__ qkvb,
                                                   ushort_t* __restrict__ vT) {
    const int t0 = blockIdx.x * 64;
    const int h = blockIdx.y, b = blockIdx.z;
    __shared__ ushort_t sm[64 * 72];
    const int tid = threadIdx.x;
    #pragma unroll
    for (int p = 0; p < 2; p++) {
        int idx = p * 256 + tid;
        int r = idx >> 3, c = idx & 7;
        *(bf16x8*)&sm[r * 72 + c * 8] =
            *(const bf16x8*)(qkvb + (size_t)(b * NT + t0 + r) * (3 * ND) + 2 * ND + h * HD + c * 8);
    }
    __syncthreads();
    #pragma unroll
    for (int p = 0; p < 2; p++) {
        int idx = p * 256 + tid;
        int d = idx >> 3, c2 = idx & 7;
        ushort_t tmp[8];
        #pragma unroll
        for (int j = 0; j < 8; j++) {
            int kp = c2 * 8 + j;
            int key = ((kp & 1) << 4) | ((kp >> 1) & 15) | (kp & 32);
            tmp[j] = sm[key * 72 + d];
        }
        *(bf16x8*)(vT + ((size_t)((b * NH + h) * HD + d)) * NT + t0 + c2 * 8) = *(bf16x8*)tmp;
    }
}

// ---------------- LayerNorm -> bf16: wave-per-row, shuffle reduce --------------
__global__ __launch_bounds__(256) void ln_kernel(const float* __restrict__ x,
                                                 const float* __restrict__ w,
                                                 const float* __restrict__ b,
                                                 ushort_t* __restrict__ out) {
    const int row  = blockIdx.x * 4 + (threadIdx.x >> 6);
    const int lane = threadIdx.x & 63;
    const float* xr = x + (size_t)row * ND;

    float4 v[3];
    #pragma unroll
    for (int s = 0; s < 3; s++) v[s] = *(const float4*)(xr + s * 256 + lane * 4);

    float sum = 0.f;
    #pragma unroll
    for (int s = 0; s < 3; s++) sum += v[s].x + v[s].y + v[s].z + v[s].w;
    #pragma unroll
    for (int off = 1; off < 64; off <<= 1) sum += __shfl_xor(sum, off, 64);
    const float mu = sum * (1.0f / ND);

    float var = 0.f;
    #pragma unroll
    for (int s = 0; s < 3; s++) {
        float a0 = v[s].x - mu, a1 = v[s].y - mu, a2 = v[s].z - mu, a3 = v[s].w - mu;
        var += a0 * a0 + a1 * a1 + a2 * a2 + a3 * a3;
    }
    #pragma unroll
    for (int off = 1; off < 64; off <<= 1) var += __shfl_xor(var, off, 64);
    const float rstd = rsqrtf(var * (1.0f / ND) + LN_EPS);

    #pragma unroll
    for (int s = 0; s < 3; s++) {
        const int col = s * 256 + lane * 4;
        float4 w4 = *(const float4*)(w + col);
        float4 b4 = *(const float4*)(b + col);
        ushort4 r;
        r.x = f2bf((v[s].x - mu) * rstd * w4.x + b4.x);
        r.y = f2bf((v[s].y - mu) * rstd * w4.y + b4.y);
        r.z = f2bf((v[s].z - mu) * rstd * w4.z + b4.z);
        r.w = f2bf((v[s].w - mu) * rstd * w4.w + b4.w);
        *(ushort4*)(out + (size_t)row * ND + col) = r;
    }
}

// ---------------- bf16 MFMA GEMM, double-buffered pipeline (128x128) -----------
// Kept for the two N=768 GEMMs, with bijective XCD-chunk swizzle (grids %8==0).
// EPI: 1 = +bias+resid -> fp32
template <int EPI>
__global__ __launch_bounds__(256) void gemm_bt(const ushort_t* __restrict__ A,
                                               const ushort_t* __restrict__ Bt,
                                               const float* __restrict__ bias,
                                               const float* __restrict__ resid,
                                               void* __restrict__ Cout,
                                               int M, int N, int K) {
    __shared__ __align__(16) ushort_t smem[2][2][128 * 32];  // [buf][A/B][...]

    const int tid  = threadIdx.x;
    const int nwg   = gridDim.x * gridDim.y;
    const int flatb = blockIdx.y * gridDim.x + blockIdx.x;
    const int q8    = nwg >> 3;
    const int swz   = (flatb & 7) * q8 + (flatb >> 3);
    const int bm   = (swz / gridDim.x) * 128;
    const int bn   = (swz % gridDim.x) * 128;
    const int lane = tid & 63;
    const int wave = tid >> 6;
    const int wm   = (wave & 1) * 64;
    const int wn   = (wave >> 1) * 64;
    const int fcol = lane & 15;
    const int quad = lane >> 4;

    f32x4 acc[4][4] = {};

    const int srow = tid >> 2, scg = (tid & 3) * 8;

    auto issue = [&](int k0, int buf) {
        #pragma unroll
        for (int p = 0; p < 2; p++) {
            const int row = srow + p * 64;
            const int flat = (p * 256 + tid) * 8;
            load_lds16(A  + (size_t)(bm + row) * K + k0 + scg, &smem[buf][0][flat]);
            load_lds16(Bt + (size_t)(bn + row) * K + k0 + scg, &smem[buf][1][flat]);
        }
    };

    issue(0, 0);
    const int KT = K >> 5;
    for (int kt = 0; kt < KT; kt++) {
        const int cur = kt & 1;
        __syncthreads();
        if (kt + 1 < KT) issue((kt + 1) << 5, cur ^ 1);

        bf16x8 a[4], b[4];
        #pragma unroll
        for (int i = 0; i < 4; i++)
            a[i] = *(const bf16x8*)&smem[cur][0][(wm + i * 16 + fcol) * 32 + quad * 8];
        #pragma unroll
        for (int j = 0; j < 4; j++)
            b[j] = *(const bf16x8*)&smem[cur][1][(wn + j * 16 + fcol) * 32 + quad * 8];
        #pragma unroll
        for (int i = 0; i < 4; i++)
            #pragma unroll
            for (int j = 0; j < 4; j++)
                acc[i][j] = __builtin_amdgcn_mfma_f32_16x16x32_bf16(a[i], b[j], acc[i][j], 0, 0, 0);
    }

    if (EPI == 1) {
        #pragma unroll
        for (int j = 0; j < 4; j++) {
            const int gcol = bn + wn + j * 16 + fcol;
            const float bs = bias[gcol];
            #pragma unroll
            for (int i = 0; i < 4; i++) {
                #pragma unroll
                for (int r = 0; r < 4; r++) {
                    const int grow = bm + wm + i * 16 + quad * 4 + r;
                    float val = acc[i][j][r] + bs + resid[(size_t)grow * N + gcol];
                    ((float*)Cout)[(size_t)grow * N + gcol] = val;
                }
            }
        }
    } else {
        __syncthreads();
        ushort_t* Cs = &smem[0][0][0] + wave * (64 * 40);
        #pragma unroll
        for (int hh = 0; hh < 2; hh++) {
            #pragma unroll
            for (int jj = 0; jj < 2; jj++) {
                const int j = hh * 2 + jj;
                const float bs = bias[bn + wn + j * 16 + fcol];
                #pragma unroll
                for (int i = 0; i < 4; i++) {
                    #pragma unroll
                    for (int r = 0; r < 4; r++) {
                        float val = acc[i][j][r] + bs;
                        if (EPI == 2) {
                            float y = 0.7978845608028654f * (val + 0.044715f * val * val * val);
                            float t = 1.0f - 2.0f / (1.0f + __expf(2.0f * y));
                            val = 0.5f * val * (1.0f + t);
                        }
                        const int lr = i * 16 + quad * 4 + r;
                        Cs[lr * 40 + jj * 16 + fcol] = f2bf(val);
                    }
                }
            }
            #pragma unroll
            for (int p = 0; p < 4; p++) {
                const int cid = p * 64 + lane;
                const int lr = cid >> 2, ck = cid & 3;
                bf16x8 vv = *(const bf16x8*)&Cs[lr * 40 + ck * 8];
                *(bf16x8*)((ushort_t*)Cout + (size_t)(bm + wm + lr) * N + bn + wn + hh * 32 + ck * 8) = vv;
            }
        }
    }
}

// ---------------- 256x256 8-phase GEMM, pipelined fragment reads ---------------
// Schedule/ledger identical to rounds 3/4 (functionally verified twice). Round-5
// register fix: SINGLE A fragment buffer (raA), time-shared between mh0 and mh1
// (HK T16 pattern). raA is reloaded with A-mh1 right AFTER P2's MFMA cluster
// consumed it (in-order issue: MFMA latches sources at issue; ds_read writeback
// lands >=30cy later -> WAR-safe; sched_barriers pin the order). Frag registers:
// 96 -> 64; arch VGPR now fits the 128 cap (256 total incl. 128 acc AGPRs at
// 8 waves/CU) -> no scratch spill (round 3: 83MB, round 4: 73MB vs 49MB ideal).
//   waits: P1:lgkm(4) P2:lgkm(0) P3:lgkm(0) P4:none (+VMW6, 12-read lookahead).
// EPI: 0 = +bias -> bf16;  2 = +bias,gelu(tanh) -> bf16
template <int EPI, int NN, int KK>
__global__ __launch_bounds__(512, 2) void gemm256(const ushort_t* __restrict__ A,
                                                  const ushort_t* __restrict__ Bt,
                                                  const float* __restrict__ bias,
                                                  ushort_t* __restrict__ Cout) {
    extern __shared__ __align__(16) ushort_t lds[];

    const int tid  = threadIdx.x;
    const int lane = tid & 63;
    const int wave = tid >> 6;     // 0..7
    const int wr   = wave >> 2;    // 0..1  (M half)
    const int wn   = wave & 3;     // 0..3  (N quarter)
    const int fcol = lane & 15;
    const int quad = lane >> 4;

    // XCD-aware chunked swizzle (nwg % 8 == 0 for both instantiations).
    const int nwg   = gridDim.x * gridDim.y;
    const int flatb = blockIdx.y * gridDim.x + blockIdx.x;
    const int q8    = nwg >> 3;
    const int swz   = (flatb & 7) * q8 + (flatb >> 3);
    const int bm    = (swz / gridDim.x) * 256;
    const int bn    = (swz % gridDim.x) * 256;

    constexpr int KT  = KK >> 6;   // 64-wide K tiles
    constexpr int NIT = KT >> 1;   // double-tile iterations

    f32x4 acc[8][4] = {};
    bf16x8 raA[4][2];              // single A buffer, time-shared mh0/mh1
    bf16x8 rb[2][2][2];            // [buf][j2][ks] B buffers

    ushort_t* const Ab = lds;           // 4 slots x 8192 ushorts
    ushort_t* const Bb = lds + 32768;   // 4 slots x 8192 ushorts

    // 4 fragment-read base addresses (all other addressing is offset: immediates)
    const unsigned f7 = (unsigned)(fcol & 7);
    const unsigned ldsA = (unsigned)(size_t)(const __attribute__((address_space(3))) ushort_t*)Ab;
    const unsigned ldsB = (unsigned)(size_t)(const __attribute__((address_space(3))) ushort_t*)Bb;
    unsigned baseA0 = ldsA + (unsigned)((wr * 64 + fcol) * 128 + ((quad) ^ f7) * 16);
    unsigned baseA1 = ldsA + (unsigned)((wr * 64 + fcol) * 128 + ((4 | quad) ^ f7) * 16);
    unsigned baseB0 = ldsB + (unsigned)((wn * 32 + fcol) * 128 + ((quad) ^ f7) * 16);
    unsigned baseB1 = ldsB + (unsigned)((wn * 32 + fcol) * 128 + ((4 | quad) ^ f7) * 16);

    auto stA = [&](int kt, int h) {
        ushort_t* dst = Ab + ((((kt & 1) << 1) | h) << 13);
        const int kk = (kt < KT ? kt : 0) << 6;   // dummy tail stages keep vmcnt ledger
        #pragma unroll
        for (int p = 0; p < 2; p++) {
            const int f = (p << 9) + tid;
            const int r = f >> 3, c = (f & 7) ^ (r & 7);
            const int gr = bm + ((r >> 6) << 7) + (h << 6) + (r & 63);
            load_lds16(A + (size_t)gr * KK + kk + c * 8, dst + f * 8);
        }
    };
    auto stB = [&](int kt, int h) {
        ushort_t* dst = Bb + ((((kt & 1) << 1) | h) << 13);
        const int kk = (kt < KT ? kt : 0) << 6;
        #pragma unroll
        for (int p = 0; p < 2; p++) {
            const int f = (p << 9) + tid;
            const int r = f >> 3, c = (f & 7) ^ (r & 7);
            const int gr = bn + ((r >> 5) << 6) + (h << 5) + (r & 31);
            load_lds16(Bt + (size_t)gr * KK + kk + c * 8, dst + f * 8);
        }
    };

// slot byte = ((PAR<<1)|S)*16384 ; subtile byte = I*2048 ; both compile-time.
#define RDA1(PAR, MH, I2) {                                                           \
    raA[I2][0] = ds_read16o<((((PAR) << 1) | (MH)) * 16384 + (I2) * 2048)>(baseA0);   \
    raA[I2][1] = ds_read16o<((((PAR) << 1) | (MH)) * 16384 + (I2) * 2048)>(baseA1); }
#define RD_A(PAR, MH) { RDA1(PAR, MH, 0) RDA1(PAR, MH, 1)                             \
                        RDA1(PAR, MH, 2) RDA1(PAR, MH, 3) }
#define RDB1(PAR, NH, BUF, J2) {                                                      \
    rb[BUF][J2][0] = ds_read16o<((((PAR) << 1) | (NH)) * 16384 + (J2) * 2048)>(baseB0);\
    rb[BUF][J2][1] = ds_read16o<((((PAR) << 1) | (NH)) * 16384 + (J2) * 2048)>(baseB1); }
#define RD_B(PAR, NH, BUF) { RDB1(PAR, NH, BUF, 0) RDB1(PAR, NH, BUF, 1) }
#define LGKM(N) { asm volatile("s_waitcnt lgkmcnt(" #N ")" ::: "memory");             \
    __builtin_amdgcn_sched_barrier(0); }
#define MMA_CORE(MH, NH, BUF) {                                                       \
    __builtin_amdgcn_sched_barrier(0);                                                \
    __builtin_amdgcn_s_setprio(1);                                                    \
    _Pragma("unroll") for (int i2 = 0; i2 < 4; i2++)                                  \
    _Pragma("unroll") for (int j2 = 0; j2 < 2; j2++)                                  \
    _Pragma("unroll") for (int ks = 0; ks < 2; ks++)                                  \
        acc[(MH) * 4 + i2][(NH) * 2 + j2] = __builtin_amdgcn_mfma_f32_16x16x32_bf16(  \
            raA[i2][ks], rb[BUF][j2][ks],                                             \
            acc[(MH) * 4 + i2][(NH) * 2 + j2], 0, 0, 0);                              \
    __builtin_amdgcn_s_setprio(0);                                                    \
    __builtin_amdgcn_sched_barrier(0); }
#define VMW6() asm volatile("s_waitcnt vmcnt(6)" ::: "memory")
#define BARR() asm volatile("s_barrier" ::: "memory")

    // prologue: tile0 (4 halves), tile1 {A-mh0, B-nh0, B-nh1}; then preload P1 frags
    stA(0, 0); stB(0, 0); stB(0, 1); stA(0, 1);
    stA(1, 0); stB(1, 0); stB(1, 1);
    VMW6();                                   // tile0 (8 oldest loads) fully landed
    BARR();
    RD_A(0, 0);                               // A(t0,mh0) -> raA
    RD_B(0, 0, 0);                            // B(t0,nh0) -> rb[0]

    #pragma unroll 1
    for (int it = 0; it < NIT; ++it) {
        const int E = it << 1, O = E + 1;
        // ---- tile E (par0; nh0@rb0, nh1@rb1) ----
        RD_B(0, 1, 1);            // B(E,nh1)
        stA(O, 1);
        LGKM(4);                  // 12 pre-reads done (raA=A(E,mh0), rb0=B(E,nh0))
        MMA_CORE(0, 0, 0);
        BARR();

        stA(E + 2, 0);
        LGKM(0);                  // B(E,nh1) done
        MMA_CORE(0, 1, 1);
        RD_A(0, 1);               // reload raA <- A(E,mh1) AFTER consumption
        BARR();

        stB(E + 2, 0);
        LGKM(0);                  // A(E,mh1) done
        MMA_CORE(1, 1, 1);
        BARR();

        MMA_CORE(1, 0, 0);        // raA(mh1), rb0 — both drained
        stB(E + 2, 1);
        VMW6();                   // tile-O slots landed (own-wave)
        RD_A(1, 0);               // pre-read A(O,mh0)
        RD_B(1, 0, 1);            // pre-read B(O,nh0) -> rb1
        BARR();

        // ---- tile O (par1; nh0@rb1, nh1@rb0) ----
        RD_B(1, 1, 0);            // B(O,nh1)
        stA(E + 2, 1);
        LGKM(4);
        MMA_CORE(0, 0, 1);
        BARR();

        stA(O + 2, 0);
        LGKM(0);
        MMA_CORE(0, 1, 0);
        RD_A(1, 1);               // reload raA <- A(O,mh1)
        BARR();

        stB(O + 2, 0);
        LGKM(0);
        MMA_CORE(1, 1, 0);
        BARR();

        MMA_CORE(1, 0, 1);
        stB(O + 2, 1);
        VMW6();
        RD_A(0, 0);               // pre-read A(E+2,mh0) (dummy on final iter)
        RD_B(0, 0, 0);            // pre-read B(E+2,nh0) -> rb0
        BARR();
    }

    // drain everything before reusing LDS for the C epilogue
    asm volatile("s_waitcnt vmcnt(0) lgkmcnt(0)" ::: "memory");
    BARR();

    // epilogue: per-wave-private LDS staging (64 rows x 64 cols per m-half, pad 72)
    ushort_t* Cs = lds + wave * (64 * 72);
    #pragma unroll
    for (int h = 0; h < 2; h++) {
        #pragma unroll
        for (int j = 0; j < 4; j++) {
            const float bs = bias[bn + wn * 64 + j * 16 + fcol];
            #pragma unroll
            for (int i2 = 0; i2 < 4; i2++) {
                #pragma unroll
                for (int r = 0; r < 4; r++) {
                    float val = acc[h * 4 + i2][j][r] + bs;
                    if (EPI == 2) {
                        float y = 0.7978845608028654f * (val + 0.044715f * val * val * val);
                        float t = 1.0f - 2.0f / (1.0f + __expf(2.0f * y));
                        val = 0.5f * val * (1.0f + t);
                    }
                    Cs[(i2 * 16 + quad * 4 + r) * 72 + j * 16 + fcol] = f2bf(val);
                }
            }
        }
        #pragma unroll
        for (int p = 0; p < 8; p++) {
            const int cid = (p << 6) + lane;
            const int lr = cid >> 3, ck = cid & 7;
            bf16x8 vv = *(const bf16x8*)&Cs[lr * 72 + ck * 8];
            *(bf16x8*)(Cout + (size_t)(bm + wr * 128 + h * 64 + lr) * NN + bn + wn * 64 + ck * 8) = vv;
        }
    }
#undef RDA1
#undef RD_A
#undef RDB1
#undef RD_B
#undef LGKM
#undef MMA_CORE
#undef VMW6
#undef BARR
}

// ---------------- MFMA flash attention: no-max softmax, l via ones-MFMA --------
__global__ __launch_bounds__(256) void flash_attn_mfma(const ushort_t* __restrict__ qkvb,
                                                       const ushort_t* __restrict__ vT,
                                                       const int* __restrict__ amask,
                                                       ushort_t* __restrict__ out) {
    const int qt = 15 - blockIdx.x;   // heavy tiles first
    const int h  = blockIdx.y;
    const int b  = blockIdx.z;
    const int q0 = qt * 64;

    __shared__ __align__(16) ushort_t QPs[64 * 64];      // Q, then reused for P
    __shared__ __align__(16) ushort_t Ks[2][64 * 64];
    __shared__ __align__(16) ushort_t Vts[2][64 * 64];

    const int tid  = threadIdx.x;
    const int lane = tid & 63;
    const int wave = tid >> 6;
    const int fcol = lane & 15;
    const int quad = lane >> 4;
    const int wq0  = wave * 16;

    #pragma unroll
    for (int p = 0; p < 2; p++) {
        int flat = p * 256 + tid;
        int r = flat >> 3, c = (flat & 7) ^ (r & 7);
        load_lds16(qkvb + (size_t)(b * NT + q0 + r) * (3 * ND) + h * HD + c * 8, &QPs[flat * 8]);
    }
    __syncthreads();

    bf16x8 aQ[2];
    {
        const int qr = wq0 + fcol;
        #pragma unroll
        for (int ks = 0; ks < 2; ks++) {
            int c = ks * 4 + quad;
            aQ[ks] = *(const bf16x8*)&QPs[qr * 64 + ((c ^ (qr & 7)) * 8)];
        }
    }

    bf16x8 bones;
    #pragma unroll
    for (int i = 0; i < 8; i++) bones[i] = (__bf16)1.0f;

    auto issueKV = [&](int cch, int buf) {
        const int kbase = cch * 64;
        #pragma unroll
        for (int p = 0; p < 2; p++) {
            int flat = p * 256 + tid;
            int r = flat >> 3, c = (flat & 7) ^ (r & 7);
            load_lds16(qkvb + (size_t)(b * NT + kbase + r) * (3 * ND) + ND + h * HD + c * 8,
                       &Ks[buf][flat * 8]);
            load_lds16(vT + ((size_t)((b * NH + h) * HD + r)) * NT + kbase + c * 8,
                       &Vts[buf][flat * 8]);
        }
    };

    f32x4 oacc[4] = {};
    f32x4 lacc = {};

    const int c_lo = (qt > 12) ? (qt - 12) : 0;
    issueKV(c_lo, 0);
    for (int cch = c_lo; cch <= qt; cch++) {
        const int cur = (cch - c_lo) & 1;
        const int kbase = cch * 64;
        __syncthreads();
        if (cch + 1 <= qt) issueKV(cch + 1, cur ^ 1);

        int am[4];
        #pragma unroll
        for (int jn = 0; jn < 4; jn++) am[jn] = amask[b * NT + kbase + jn * 16 + fcol];
        const int amok_lane = (am[0] != 0) & (am[1] != 0) & (am[2] != 0) & (am[3] != 0);
        const bool fast = (cch < qt) && (cch >= qt - 11) && __all(amok_lane);

        f32x4 sc[4] = {};
        #pragma unroll
        for (int ks = 0; ks < 2; ks++) {
            #pragma unroll
            for (int jn = 0; jn < 4; jn++) {
                const int kr = jn * 16 + fcol;
                bf16x8 bk = *(const bf16x8*)&Ks[cur][kr * 64 + (((ks * 4 + quad) ^ (kr & 7)) * 8)];
                sc[jn] = __builtin_amdgcn_mfma_f32_16x16x32_bf16(aQ[ks], bk, sc[jn], 0, 0, 0);
            }
        }

        float pvv[4][4];
        if (fast) {
            #pragma unroll
            for (int jn = 0; jn < 4; jn++)
                #pragma unroll
                for (int r = 0; r < 4; r++)
                    pvv[jn][r] = __builtin_amdgcn_exp2f(sc[jn][r] * SCL2);
        } else {
            #pragma unroll
            for (int jn = 0; jn < 4; jn++) {
                const int jg = kbase + jn * 16 + fcol;
                const bool amok = (am[jn] != 0);
                #pragma unroll
                for (int r = 0; r < 4; r++) {
                    const int ig = q0 + wq0 + quad * 4 + r;
                    bool keep = (jg <= ig) && (jg >= ig - (WINDOW - 1)) && amok;
                    float s = keep ? sc[jn][r] * SCL2 : -1e38f;
                    pvv[jn][r] = __builtin_amdgcn_exp2f(s);
                }
            }
        }

        #pragma unroll
        for (int half = 0; half < 2; half++) {
            const int cbase = half * 4 + (fcol >> 2);
            const int off = (fcol & 3) * 2;
            #pragma unroll
            for (int r = 0; r < 4; r++) {
                const int row = wq0 + quad * 4 + r;
                unsigned int pk = (unsigned int)f2bf(pvv[half * 2][r]) |
                                  ((unsigned int)f2bf(pvv[half * 2 + 1][r]) << 16);
                *(unsigned int*)&QPs[row * 64 + ((cbase ^ (row & 7)) * 8) + off] = pk;
            }
        }

        #pragma unroll
        for (int ks = 0; ks < 2; ks++) {
            const int pr = wq0 + fcol;
            bf16x8 ap = *(const bf16x8*)&QPs[pr * 64 + (((ks * 4 + quad) ^ (pr & 7)) * 8)];
            lacc = __builtin_amdgcn_mfma_f32_16x16x32_bf16(ap, bones, lacc, 0, 0, 0);
            #pragma unroll
            for (int jd = 0; jd < 4; jd++) {
                const int vr = jd * 16 + fcol;
                bf16x8 bv = *(const bf16x8*)&Vts[cur][vr * 64 + (((ks * 4 + quad) ^ (vr & 7)) * 8)];
                oacc[jd] = __builtin_amdgcn_mfma_f32_16x16x32_bf16(ap, bv, oacc[jd], 0, 0, 0);
            }
        }
    }

    #pragma unroll
    for (int r = 0; r < 4; r++) {
        const float inv = 1.0f / lacc[r];
        const size_t row = (size_t)(b * NT + q0 + wq0 + quad * 4 + r);
        #pragma unroll
        for (int jd = 0; jd < 4; jd++)
            out[row * ND + h * HD + jd * 16 + fcol] = f2bf(oacc[jd][r] * inv);
    }
}

extern "C" void kernel_launch(void* const* d_in, const int* in_sizes, int n_in,
                              void* d_out, int out_size, void* d_ws, size_t ws_size,
                              hipStream_t stream) {
    const float* x        = (const float*)d_in[0];
    const int*   amask    = (const int*)  d_in[1];
    const float* ln1_w    = (const float*)d_in[2];
    const float* ln1_b    = (const float*)d_in[3];
    const float* w_attn   = (const float*)d_in[4];
    const float* b_attn   = (const float*)d_in[5];
    const float* w_proj   = (const float*)d_in[6];
    const float* b_proj   = (const float*)d_in[7];
    const float* ln2_w    = (const float*)d_in[8];
    const float* ln2_b    = (const float*)d_in[9];
    const float* w_fc     = (const float*)d_in[10];
    const float* b_fc     = (const float*)d_in[11];
    const float* w_fcp    = (const float*)d_in[12];
    const float* b_fcp    = (const float*)d_in[13];
    float* out = (float*)d_out;

    ushort_t* ws = (ushort_t*)d_ws;
    ushort_t* qkvb   = ws;                               // BT*3*ND
    ushort_t* x1b    = qkvb + (size_t)BT * 3 * ND;       // BT*ND
    ushort_t* attn_b = x1b + (size_t)BT * ND;            // BT*ND
    ushort_t* hbuf   = attn_b + (size_t)BT * ND;         // BT*4*ND
    ushort_t* vTb    = hbuf + (size_t)BT * 4 * ND;       // BT*ND
    ushort_t* wA_T   = vTb + (size_t)BT * ND;            // 2304*768
    ushort_t* wP_T   = wA_T + (size_t)2304 * 768;        // 768*768
    ushort_t* wF_T   = wP_T + (size_t)768 * 768;         // 3072*768
    ushort_t* wFP_T  = wF_T + (size_t)3072 * 768;        // 768*3072

    static bool attr_set = false;
    if (!attr_set) {
        hipFuncSetAttribute((const void*)gemm256<0, 2304, 768>, hipFuncAttributeMaxDynamicSharedMemorySize, 131072);
        hipFuncSetAttribute((const void*)gemm256<2, 3072, 768>, hipFuncAttributeMaxDynamicSharedMemorySize, 131072);
        attr_set = true;
    }

    transpose_all<<<6912, 256, 0, stream>>>(w_attn, wA_T, w_proj, wP_T, w_fc, wF_T, w_fcp, wFP_T);

    ln_kernel<<<BT / 4, 256, 0, stream>>>(x, ln1_w, ln1_b, x1b);
    gemm256<0, 2304, 768><<<dim3(2304 / 256, BT / 256), 512, 131072, stream>>>(x1b, wA_T, b_attn, qkvb);
    transpose_v<<<dim3(16, NH, NB), 256, 0, stream>>>(qkvb, vTb);
    flash_attn_mfma<<<dim3(16, NH, NB), 256, 0, stream>>>(qkvb, vTb, amask, attn_b);
    gemm_bt<1><<<dim3(768 / 128, BT / 128), 256, 0, stream>>>(attn_b, wP_T, b_proj, x, out, BT, ND, ND);
    ln_kernel<<<BT / 4, 256, 0, stream>>>(out, ln2_w, ln2_b, x1b);
    gemm256<2, 3072, 768><<<dim3(3072 / 256, BT / 256), 512, 131072, stream>>>(x1b, wF_T, b_fc, hbuf);
    gemm_bt<1><<<dim3(768 / 128, BT / 128), 256, 0, stream>>>(hbuf, wFP_T, b_fcp, out, out, BT, ND, 4 * ND);
}

// Round 6
// 367.999 us; speedup vs baseline: 1.2501x; 1.0054x over previous
//
#include <hip/hip_runtime.h>
#include <hip/hip_bf16.h>
#include <math.h>

#define NB 8
#define NT 1024
#define ND 768
#define NH 12
#define HD 64
#define WINDOW 768
#define LN_EPS 1e-5f
#define NEGF -3.4028234663852886e38f
#define SCL2 0.18033688011112042f   // 0.125 * log2(e)

static const int BT = NB * NT;  // 8192 rows

typedef __bf16 bf16x8 __attribute__((ext_vector_type(8)));
typedef float  f32x4  __attribute__((ext_vector_type(4)));
typedef unsigned short ushort_t;

__device__ __forceinline__ unsigned short f2bf(float f) {
    __hip_bfloat16 h = __float2bfloat16(f);
    return __builtin_bit_cast(unsigned short, h);
}

// async global->LDS, 16B per lane. LDS dest = wave-uniform base + lane*16.
__device__ __forceinline__ void load_lds16(const void* g, void* l) {
    __builtin_amdgcn_global_load_lds((const __attribute__((address_space(1))) unsigned int*)g,
                                     (__attribute__((address_space(3))) unsigned int*)l,
                                     16, 0, 0);
}

// inline-asm ds_read_b128 with compile-time offset immediate: ONE base VGPR serves
// all fragment reads of a class (slot + subtile folded into offset:IMM).
template <int IMM>
__device__ __forceinline__ bf16x8 ds_read16o(unsigned base) {
    bf16x8 r;
    asm volatile("ds_read_b128 %0, %1 offset:%2" : "=v"(r) : "v"(base), "n"(IMM));
    return r;
}

// ---------------- all weight transposes fused: wT[n][k] = bf16(w[k][n]) --------
__global__ __launch_bounds__(256) void transpose_all(const float* __restrict__ w0, ushort_t* __restrict__ t0v,
                                                     const float* __restrict__ w1, ushort_t* __restrict__ t1v,
                                                     const float* __restrict__ w2, ushort_t* __restrict__ t2v,
                                                     const float* __restrict__ w3, ushort_t* __restrict__ t3v) {
    int bid = blockIdx.x;
    const float* w; ushort_t* wt; int K, N;
    if (bid < 1728)                    { w = w0; wt = t0v; K = 768;  N = 2304; }
    else if ((bid -= 1728) < 576)      { w = w1; wt = t1v; K = 768;  N = 768;  }
    else if ((bid -= 576) < 2304)      { w = w2; wt = t2v; K = 768;  N = 3072; }
    else       { bid -= 2304;            w = w3; wt = t3v; K = 3072; N = 768;  }
    const int nxt = N / 32;
    const int n0 = (bid % nxt) * 32, k0 = (bid / nxt) * 32;
    __shared__ float t[32][33];
    const int tx = threadIdx.x & 31, ty = threadIdx.x >> 5;  // 32 x 8
    for (int r = ty; r < 32; r += 8)
        t[r][tx] = w[(size_t)(k0 + r) * N + n0 + tx];
    __syncthreads();
    for (int r = ty; r < 32; r += 8)
        wt[(size_t)(n0 + r) * K + k0 + tx] = f2bf(t[tx][r]);
}

// ---------------- V transpose (pi-permuted keys): vT[b][h][d][t'] --------------
__global__ __launch_bounds__(256) void transpose_v(const ushort_t* __restrict__ qkvb,
                                                   ushort_t* __restrict__ vT) {
    const int t0 = blockIdx.x * 64;
    const int h = blockIdx.y, b = blockIdx.z;
    __shared__ ushort_t sm[64 * 72];
    const int tid = threadIdx.x;
    #pragma unroll
    for (int p = 0; p < 2; p++) {
        int idx = p * 256 + tid;
        int r = idx >> 3, c = idx & 7;
        *(bf16x8*)&sm[r * 72 + c * 8] =
            *(const bf16x8*)(qkvb + (size_t)(b * NT + t0 + r) * (3 * ND) + 2 * ND + h * HD + c * 8);
    }
    __syncthreads();
    #pragma unroll
    for (int p = 0; p < 2; p++) {
        int idx = p * 256 + tid;
        int d = idx >> 3, c2 = idx & 7;
        ushort_t tmp[8];
        #pragma unroll
        for (int j = 0; j < 8; j++) {
            int kp = c2 * 8 + j;
            int key = ((kp & 1) << 4) | ((kp >> 1) & 15) | (kp & 32);
            tmp[j] = sm[key * 72 + d];
        }
        *(bf16x8*)(vT + ((size_t)((b * NH + h) * HD + d)) * NT + t0 + c2 * 8) = *(bf16x8*)tmp;
    }
}

// ---------------- LayerNorm -> bf16: wave-per-row, shuffle reduce --------------
__global__ __launch_bounds__(256) void ln_kernel(const float* __restrict__ x,
                                                 const float* __restrict__ w,
                                                 const float* __restrict__ b,
                                                 ushort_t* __restrict__ out) {
    const int row  = blockIdx.x * 4 + (threadIdx.x >> 6);
    const int lane = threadIdx.x & 63;
    const float* xr = x + (size_t)row * ND;

    float4 v[3];
    #pragma unroll
    for (int s = 0; s < 3; s++) v[s] = *(const float4*)(xr + s * 256 + lane * 4);

    float sum = 0.f;
    #pragma unroll
    for (int s = 0; s < 3; s++) sum += v[s].x + v[s].y + v[s].z + v[s].w;
    #pragma unroll
    for (int off = 1; off < 64; off <<= 1) sum += __shfl_xor(sum, off, 64);
    const float mu = sum * (1.0f / ND);

    float var = 0.f;
    #pragma unroll
    for (int s = 0; s < 3; s++) {
        float a0 = v[s].x - mu, a1 = v[s].y - mu, a2 = v[s].z - mu, a3 = v[s].w - mu;
        var += a0 * a0 + a1 * a1 + a2 * a2 + a3 * a3;
    }
    #pragma unroll
    for (int off = 1; off < 64; off <<= 1) var += __shfl_xor(var, off, 64);
    const float rstd = rsqrtf(var * (1.0f / ND) + LN_EPS);

    #pragma unroll
    for (int s = 0; s < 3; s++) {
        const int col = s * 256 + lane * 4;
        float4 w4 = *(const float4*)(w + col);
        float4 b4 = *(const float4*)(b + col);
        ushort4 r;
        r.x = f2bf((v[s].x - mu) * rstd * w4.x + b4.x);
        r.y = f2bf((v[s].y - mu) * rstd * w4.y + b4.y);
        r.z = f2bf((v[s].z - mu) * rstd * w4.z + b4.z);
        r.w = f2bf((v[s].w - mu) * rstd * w4.w + b4.w);
        *(ushort4*)(out + (size_t)row * ND + col) = r;
    }
}

// ---------------- bf16 MFMA GEMM, double-buffered pipeline (128x128) -----------
// Kept for the two N=768 GEMMs, with bijective XCD-chunk swizzle (grids %8==0).
// EPI: 1 = +bias+resid -> fp32
template <int EPI>
__global__ __launch_bounds__(256) void gemm_bt(const ushort_t* __restrict__ A,
                                               const ushort_t* __restrict__ Bt,
                                               const float* __restrict__ bias,
                                               const float* __restrict__ resid,
                                               void* __restrict__ Cout,
                                               int M, int N, int K) {
    __shared__ __align__(16) ushort_t smem[2][2][128 * 32];  // [buf][A/B][...]

    const int tid  = threadIdx.x;
    const int nwg   = gridDim.x * gridDim.y;
    const int flatb = blockIdx.y * gridDim.x + blockIdx.x;
    const int q8    = nwg >> 3;
    const int swz   = (flatb & 7) * q8 + (flatb >> 3);
    const int bm   = (swz / gridDim.x) * 128;
    const int bn   = (swz % gridDim.x) * 128;
    const int lane = tid & 63;
    const int wave = tid >> 6;
    const int wm   = (wave & 1) * 64;
    const int wn   = (wave >> 1) * 64;
    const int fcol = lane & 15;
    const int quad = lane >> 4;

    f32x4 acc[4][4] = {};

    const int srow = tid >> 2, scg = (tid & 3) * 8;

    auto issue = [&](int k0, int buf) {
        #pragma unroll
        for (int p = 0; p < 2; p++) {
            const int row = srow + p * 64;
            const int flat = (p * 256 + tid) * 8;
            load_lds16(A  + (size_t)(bm + row) * K + k0 + scg, &smem[buf][0][flat]);
            load_lds16(Bt + (size_t)(bn + row) * K + k0 + scg, &smem[buf][1][flat]);
        }
    };

    issue(0, 0);
    const int KT = K >> 5;
    for (int kt = 0; kt < KT; kt++) {
        const int cur = kt & 1;
        __syncthreads();
        if (kt + 1 < KT) issue((kt + 1) << 5, cur ^ 1);

        bf16x8 a[4], b[4];
        #pragma unroll
        for (int i = 0; i < 4; i++)
            a[i] = *(const bf16x8*)&smem[cur][0][(wm + i * 16 + fcol) * 32 + quad * 8];
        #pragma unroll
        for (int j = 0; j < 4; j++)
            b[j] = *(const bf16x8*)&smem[cur][1][(wn + j * 16 + fcol) * 32 + quad * 8];
        #pragma unroll
        for (int i = 0; i < 4; i++)
            #pragma unroll
            for (int j = 0; j < 4; j++)
                acc[i][j] = __builtin_amdgcn_mfma_f32_16x16x32_bf16(a[i], b[j], acc[i][j], 0, 0, 0);
    }

    if (EPI == 1) {
        #pragma unroll
        for (int j = 0; j < 4; j++) {
            const int gcol = bn + wn + j * 16 + fcol;
            const float bs = bias[gcol];
            #pragma unroll
            for (int i = 0; i < 4; i++) {
                #pragma unroll
                for (int r = 0; r < 4; r++) {
                    const int grow = bm + wm + i * 16 + quad * 4 + r;
                    float val = acc[i][j][r] + bs + resid[(size_t)grow * N + gcol];
                    ((float*)Cout)[(size_t)grow * N + gcol] = val;
                }
            }
        }
    } else {
        __syncthreads();
        ushort_t* Cs = &smem[0][0][0] + wave * (64 * 40);
        #pragma unroll
        for (int hh = 0; hh < 2; hh++) {
            #pragma unroll
            for (int jj = 0; jj < 2; jj++) {
                const int j = hh * 2 + jj;
                const float bs = bias[bn + wn + j * 16 + fcol];
                #pragma unroll
                for (int i = 0; i < 4; i++) {
                    #pragma unroll
                    for (int r = 0; r < 4; r++) {
                        float val = acc[i][j][r] + bs;
                        if (EPI == 2) {
                            float y = 0.7978845608028654f * (val + 0.044715f * val * val * val);
                            float t = 1.0f - 2.0f / (1.0f + __expf(2.0f * y));
                            val = 0.5f * val * (1.0f + t);
                        }
                        const int lr = i * 16 + quad * 4 + r;
                        Cs[lr * 40 + jj * 16 + fcol] = f2bf(val);
                    }
                }
            }
            #pragma unroll
            for (int p = 0; p < 4; p++) {
                const int cid = p * 64 + lane;
                const int lr = cid >> 2, ck = cid & 3;
                bf16x8 vv = *(const bf16x8*)&Cs[lr * 40 + ck * 8];
                *(bf16x8*)((ushort_t*)Cout + (size_t)(bm + wm + lr) * N + bn + wn + hh * 32 + ck * 8) = vv;
            }
        }
    }
}

// ---------------- 256x256 GEMM, 4 merged phases (barrier-halved round 5) -------
// EXACT round-5 instruction sequence (3x harness-verified: stages, counted
// lgkm/vmcnt ledger, pre-read placement, register plan all unchanged) with the 4
// intra-pair barriers deleted: phases merge P1+P2 / P3+P4 / P5+P6 / P7+P8.
// MFMA runs double to 32 per barrier window; sync events halve 48 -> 24 / block.
// Safety audit of each removed barrier:
//  - A-mh1 pre-read cross-wave cover comes from the PREVIOUS VMW6+BARR (intact).
//  - every stage that overwrites a slot still has >=1 barrier after the LGKM that
//    drained the slot's last reads (X4's overwrite of B(E,1): read drained by
//    MP1's LGKM(0), MP1-end barrier intervenes).
//  - VMW(6) counts re-derived for 4 stages/merged-pair: leaves {X2,X3,X4} resp.
//    {X6,X7,X8} in flight == round-5 landed-guarantees exactly.
// EPI: 0 = +bias -> bf16;  2 = +bias,gelu(tanh) -> bf16
template <int EPI, int NN, int KK>
__global__ __launch_bounds__(512, 2) void gemm256(const ushort_t* __restrict__ A,
                                                  const ushort_t* __restrict__ Bt,
                                                  const float* __restrict__ bias,
                                                  ushort_t* __restrict__ Cout) {
    extern __shared__ __align__(16) ushort_t lds[];

    const int tid  = threadIdx.x;
    const int lane = tid & 63;
    const int wave = tid >> 6;     // 0..7
    const int wr   = wave >> 2;    // 0..1  (M half)
    const int wn   = wave & 3;     // 0..3  (N quarter)
    const int fcol = lane & 15;
    const int quad = lane >> 4;

    // XCD-aware chunked swizzle (nwg % 8 == 0 for both instantiations).
    const int nwg   = gridDim.x * gridDim.y;
    const int flatb = blockIdx.y * gridDim.x + blockIdx.x;
    const int q8    = nwg >> 3;
    const int swz   = (flatb & 7) * q8 + (flatb >> 3);
    const int bm    = (swz / gridDim.x) * 256;
    const int bn    = (swz % gridDim.x) * 256;

    constexpr int KT  = KK >> 6;   // 64-wide K tiles
    constexpr int NIT = KT >> 1;   // double-tile iterations

    f32x4 acc[8][4] = {};
    bf16x8 raA[4][2];              // single A buffer, time-shared mh0/mh1
    bf16x8 rb[2][2][2];            // [buf][j2][ks] B buffers

    ushort_t* const Ab = lds;           // 4 slots x 8192 ushorts
    ushort_t* const Bb = lds + 32768;   // 4 slots x 8192 ushorts

    // 4 fragment-read base addresses (all other addressing is offset: immediates)
    const unsigned f7 = (unsigned)(fcol & 7);
    const unsigned ldsA = (unsigned)(size_t)(const __attribute__((address_space(3))) ushort_t*)Ab;
    const unsigned ldsB = (unsigned)(size_t)(const __attribute__((address_space(3))) ushort_t*)Bb;
    unsigned baseA0 = ldsA + (unsigned)((wr * 64 + fcol) * 128 + ((quad) ^ f7) * 16);
    unsigned baseA1 = ldsA + (unsigned)((wr * 64 + fcol) * 128 + ((4 | quad) ^ f7) * 16);
    unsigned baseB0 = ldsB + (unsigned)((wn * 32 + fcol) * 128 + ((quad) ^ f7) * 16);
    unsigned baseB1 = ldsB + (unsigned)((wn * 32 + fcol) * 128 + ((4 | quad) ^ f7) * 16);

    auto stA = [&](int kt, int h) {
        ushort_t* dst = Ab + ((((kt & 1) << 1) | h) << 13);
        const int kk = (kt < KT ? kt : 0) << 6;   // dummy tail stages keep vmcnt ledger
        #pragma unroll
        for (int p = 0; p < 2; p++) {
            const int f = (p << 9) + tid;
            const int r = f >> 3, c = (f & 7) ^ (r & 7);
            const int gr = bm + ((r >> 6) << 7) + (h << 6) + (r & 63);
            load_lds16(A + (size_t)gr * KK + kk + c * 8, dst + f * 8);
        }
    };
    auto stB = [&](int kt, int h) {
        ushort_t* dst = Bb + ((((kt & 1) << 1) | h) << 13);
        const int kk = (kt < KT ? kt : 0) << 6;
        #pragma unroll
        for (int p = 0; p < 2; p++) {
            const int f = (p << 9) + tid;
            const int r = f >> 3, c = (f & 7) ^ (r & 7);
            const int gr = bn + ((r >> 5) << 6) + (h << 5) + (r & 31);
            load_lds16(Bt + (size_t)gr * KK + kk + c * 8, dst + f * 8);
        }
    };

// slot byte = ((PAR<<1)|S)*16384 ; subtile byte = I*2048 ; both compile-time.
#define RDA1(PAR, MH, I2) {                                                           \
    raA[I2][0] = ds_read16o<((((PAR) << 1) | (MH)) * 16384 + (I2) * 2048)>(baseA0);   \
    raA[I2][1] = ds_read16o<((((PAR) << 1) | (MH)) * 16384 + (I2) * 2048)>(baseA1); }
#define RD_A(PAR, MH) { RDA1(PAR, MH, 0) RDA1(PAR, MH, 1)                             \
                        RDA1(PAR, MH, 2) RDA1(PAR, MH, 3) }
#define RDB1(PAR, NH, BUF, J2) {                                                      \
    rb[BUF][J2][0] = ds_read16o<((((PAR) << 1) | (NH)) * 16384 + (J2) * 2048)>(baseB0);\
    rb[BUF][J2][1] = ds_read16o<((((PAR) << 1) | (NH)) * 16384 + (J2) * 2048)>(baseB1); }
#define RD_B(PAR, NH, BUF) { RDB1(PAR, NH, BUF, 0) RDB1(PAR, NH, BUF, 1) }
#define LGKM(N) { asm volatile("s_waitcnt lgkmcnt(" #N ")" ::: "memory");             \
    __builtin_amdgcn_sched_barrier(0); }
#define MMA_CORE(MH, NH, BUF) {                                                       \
    __builtin_amdgcn_sched_barrier(0);                                                \
    __builtin_amdgcn_s_setprio(1);                                                    \
    _Pragma("unroll") for (int i2 = 0; i2 < 4; i2++)                                  \
    _Pragma("unroll") for (int j2 = 0; j2 < 2; j2++)                                  \
    _Pragma("unroll") for (int ks = 0; ks < 2; ks++)                                  \
        acc[(MH) * 4 + i2][(NH) * 2 + j2] = __builtin_amdgcn_mfma_f32_16x16x32_bf16(  \
            raA[i2][ks], rb[BUF][j2][ks],                                             \
            acc[(MH) * 4 + i2][(NH) * 2 + j2], 0, 0, 0);                              \
    __builtin_amdgcn_s_setprio(0);                                                    \
    __builtin_amdgcn_sched_barrier(0); }
#define VMW6() asm volatile("s_waitcnt vmcnt(6)" ::: "memory")
#define BARR() asm volatile("s_barrier" ::: "memory")

    // prologue: tile0 (4 halves), tile1 {A-mh0, B-nh0, B-nh1}; then preload frags
    stA(0, 0); stB(0, 0); stB(0, 1); stA(0, 1);
    stA(1, 0); stB(1, 0); stB(1, 1);
    VMW6();                                   // tile0 (8 oldest loads) fully landed
    BARR();
    RD_A(0, 0);                               // A(t0,mh0) -> raA
    RD_B(0, 0, 0);                            // B(t0,nh0) -> rb[0]

    #pragma unroll 1
    for (int it = 0; it < NIT; ++it) {
        const int E = it << 1, O = E + 1;
        // ---- MP1 = tile E, quadrants (0,0)+(0,1) ----
        RD_B(0, 1, 1);            // B(E,nh1)
        stA(O, 1);                // X1
        LGKM(4);                  // 12 pre-reads done (raA=A(E,mh0), rb0=B(E,nh0))
        MMA_CORE(0, 0, 0);
        stA(E + 2, 0);            // X2
        LGKM(0);                  // B(E,nh1) done
        MMA_CORE(0, 1, 1);
        RD_A(0, 1);               // reload raA <- A(E,mh1) AFTER consumption
        BARR();

        // ---- MP2 = tile E, quadrants (1,1)+(1,0) ----
        stB(E + 2, 0);            // X3
        LGKM(0);                  // A(E,mh1) done
        MMA_CORE(1, 1, 1);
        MMA_CORE(1, 0, 0);        // operands already drained
        stB(E + 2, 1);            // X4
        VMW6();                   // guarantees <=X1 landed (tile-O slots)
        RD_A(1, 0);               // pre-read A(O,mh0)
        RD_B(1, 0, 1);            // pre-read B(O,nh0) -> rb1
        BARR();

        // ---- MP3 = tile O, quadrants (0,0)+(0,1) ----
        RD_B(1, 1, 0);            // B(O,nh1)
        stA(E + 2, 1);            // X5
        LGKM(4);
        MMA_CORE(0, 0, 1);
        stA(O + 2, 0);            // X6
        LGKM(0);
        MMA_CORE(0, 1, 0);
        RD_A(1, 1);               // reload raA <- A(O,mh1)
        BARR();

        // ---- MP4 = tile O, quadrants (1,1)+(1,0) ----
        stB(O + 2, 0);            // X7
        LGKM(0);
        MMA_CORE(1, 1, 0);
        MMA_CORE(1, 0, 1);
        stB(O + 2, 1);            // X8
        VMW6();                   // guarantees <=X5 landed
        RD_A(0, 0);               // pre-read A(E+2,mh0) (dummy on final iter)
        RD_B(0, 0, 0);            // pre-read B(E+2,nh0) -> rb0
        BARR();
    }

    // drain everything before reusing LDS for the C epilogue
    asm volatile("s_waitcnt vmcnt(0) lgkmcnt(0)" ::: "memory");
    BARR();

    // epilogue: per-wave-private LDS staging (64 rows x 64 cols per m-half, pad 72)
    ushort_t* Cs = lds + wave * (64 * 72);
    #pragma unroll
    for (int h = 0; h < 2; h++) {
        #pragma unroll
        for (int j = 0; j < 4; j++) {
            const float bs = bias[bn + wn * 64 + j * 16 + fcol];
            #pragma unroll
            for (int i2 = 0; i2 < 4; i2++) {
                #pragma unroll
                for (int r = 0; r < 4; r++) {
                    float val = acc[h * 4 + i2][j][r] + bs;
                    if (EPI == 2) {
                        float y = 0.7978845608028654f * (val + 0.044715f * val * val * val);
                        float t = 1.0f - 2.0f / (1.0f + __expf(2.0f * y));
                        val = 0.5f * val * (1.0f + t);
                    }
                    Cs[(i2 * 16 + quad * 4 + r) * 72 + j * 16 + fcol] = f2bf(val);
                }
            }
        }
        #pragma unroll
        for (int p = 0; p < 8; p++) {
            const int cid = (p << 6) + lane;
            const int lr = cid >> 3, ck = cid & 7;
            bf16x8 vv = *(const bf16x8*)&Cs[lr * 72 + ck * 8];
            *(bf16x8*)(Cout + (size_t)(bm + wr * 128 + h * 64 + lr) * NN + bn + wn * 64 + ck * 8) = vv;
        }
    }
#undef RDA1
#undef RD_A
#undef RDB1
#undef RD_B
#undef LGKM
#undef MMA_CORE
#undef VMW6
#undef BARR
}

// ---------------- MFMA flash attention: no-max softmax, l via ones-MFMA --------
__global__ __launch_bounds__(256) void flash_attn_mfma(const ushort_t* __restrict__ qkvb,
                                                       const ushort_t* __restrict__ vT,
                                                       const int* __restrict__ amask,
                                                       ushort_t* __restrict__ out) {
    const int qt = 15 - blockIdx.x;   // heavy tiles first
    const int h  = blockIdx.y;
    const int b  = blockIdx.z;
    const int q0 = qt * 64;

    __shared__ __align__(16) ushort_t QPs[64 * 64];      // Q, then reused for P
    __shared__ __align__(16) ushort_t Ks[2][64 * 64];
    __shared__ __align__(16) ushort_t Vts[2][64 * 64];

    const int tid  = threadIdx.x;
    const int lane = tid & 63;
    const int wave = tid >> 6;
    const int fcol = lane & 15;
    const int quad = lane >> 4;
    const int wq0  = wave * 16;

    #pragma unroll
    for (int p = 0; p < 2; p++) {
        int flat = p * 256 + tid;
        int r = flat >> 3, c = (flat & 7) ^ (r & 7);
        load_lds16(qkvb + (size_t)(b * NT + q0 + r) * (3 * ND) + h * HD + c * 8, &QPs[flat * 8]);
    }
    __syncthreads();

    bf16x8 aQ[2];
    {
        const int qr = wq0 + fcol;
        #pragma unroll
        for (int ks = 0; ks < 2; ks++) {
            int c = ks * 4 + quad;
            aQ[ks] = *(const bf16x8*)&QPs[qr * 64 + ((c ^ (qr & 7)) * 8)];
        }
    }

    bf16x8 bones;
    #pragma unroll
    for (int i = 0; i < 8; i++) bones[i] = (__bf16)1.0f;

    auto issueKV = [&](int cch, int buf) {
        const int kbase = cch * 64;
        #pragma unroll
        for (int p = 0; p < 2; p++) {
            int flat = p * 256 + tid;
            int r = flat >> 3, c = (flat & 7) ^ (r & 7);
            load_lds16(qkvb + (size_t)(b * NT + kbase + r) * (3 * ND) + ND + h * HD + c * 8,
                       &Ks[buf][flat * 8]);
            load_lds16(vT + ((size_t)((b * NH + h) * HD + r)) * NT + kbase + c * 8,
                       &Vts[buf][flat * 8]);
        }
    };

    f32x4 oacc[4] = {};
    f32x4 lacc = {};

    const int c_lo = (qt > 12) ? (qt - 12) : 0;
    issueKV(c_lo, 0);
    for (int cch = c_lo; cch <= qt; cch++) {
        const int cur = (cch - c_lo) & 1;
        const int kbase = cch * 64;
        __syncthreads();
        if (cch + 1 <= qt) issueKV(cch + 1, cur ^ 1);

        int am[4];
        #pragma unroll
        for (int jn = 0; jn < 4; jn++) am[jn] = amask[b * NT + kbase + jn * 16 + fcol];
        const int amok_lane = (am[0] != 0) & (am[1] != 0) & (am[2] != 0) & (am[3] != 0);
        const bool fast = (cch < qt) && (cch >= qt - 11) && __all(amok_lane);

        f32x4 sc[4] = {};
        #pragma unroll
        for (int ks = 0; ks < 2; ks++) {
            #pragma unroll
            for (int jn = 0; jn < 4; jn++) {
                const int kr = jn * 16 + fcol;
                bf16x8 bk = *(const bf16x8*)&Ks[cur][kr * 64 + (((ks * 4 + quad) ^ (kr & 7)) * 8)];
                sc[jn] = __builtin_amdgcn_mfma_f32_16x16x32_bf16(aQ[ks], bk, sc[jn], 0, 0, 0);
            }
        }

        float pvv[4][4];
        if (fast) {
            #pragma unroll
            for (int jn = 0; jn < 4; jn++)
                #pragma unroll
                for (int r = 0; r < 4; r++)
                    pvv[jn][r] = __builtin_amdgcn_exp2f(sc[jn][r] * SCL2);
        } else {
            #pragma unroll
            for (int jn = 0; jn < 4; jn++) {
                const int jg = kbase + jn * 16 + fcol;
                const bool amok = (am[jn] != 0);
                #pragma unroll
                for (int r = 0; r < 4; r++) {
                    const int ig = q0 + wq0 + quad * 4 + r;
                    bool keep = (jg <= ig) && (jg >= ig - (WINDOW - 1)) && amok;
                    float s = keep ? sc[jn][r] * SCL2 : -1e38f;
                    pvv[jn][r] = __builtin_amdgcn_exp2f(s);
                }
            }
        }

        #pragma unroll
        for (int half = 0; half < 2; half++) {
            const int cbase = half * 4 + (fcol >> 2);
            const int off = (fcol & 3) * 2;
            #pragma unroll
            for (int r = 0; r < 4; r++) {
                const int row = wq0 + quad * 4 + r;
                unsigned int pk = (unsigned int)f2bf(pvv[half * 2][r]) |
                                  ((unsigned int)f2bf(pvv[half * 2 + 1][r]) << 16);
                *(unsigned int*)&QPs[row * 64 + ((cbase ^ (row & 7)) * 8) + off] = pk;
            }
        }

        #pragma unroll
        for (int ks = 0; ks < 2; ks++) {
            const int pr = wq0 + fcol;
            bf16x8 ap = *(const bf16x8*)&QPs[pr * 64 + (((ks * 4 + quad) ^ (pr & 7)) * 8)];
            lacc = __builtin_amdgcn_mfma_f32_16x16x32_bf16(ap, bones, lacc, 0, 0, 0);
            #pragma unroll
            for (int jd = 0; jd < 4; jd++) {
                const int vr = jd * 16 + fcol;
                bf16x8 bv = *(const bf16x8*)&Vts[cur][vr * 64 + (((ks * 4 + quad) ^ (vr & 7)) * 8)];
                oacc[jd] = __builtin_amdgcn_mfma_f32_16x16x32_bf16(ap, bv, oacc[jd], 0, 0, 0);
            }
        }
    }

    #pragma unroll
    for (int r = 0; r < 4; r++) {
        const float inv = 1.0f / lacc[r];
        const size_t row = (size_t)(b * NT + q0 + wq0 + quad * 4 + r);
        #pragma unroll
        for (int jd = 0; jd < 4; jd++)
            out[row * ND + h * HD + jd * 16 + fcol] = f2bf(oacc[jd][r] * inv);
    }
}

extern "C" void kernel_launch(void* const* d_in, const int* in_sizes, int n_in,
                              void* d_out, int out_size, void* d_ws, size_t ws_size,
                              hipStream_t stream) {
    const float* x        = (const float*)d_in[0];
    const int*   amask    = (const int*)  d_in[1];
    const float* ln1_w    = (const float*)d_in[2];
    const float* ln1_b    = (const float*)d_in[3];
    const float* w_attn   = (const float*)d_in[4];
    const float* b_attn   = (const float*)d_in[5];
    const float* w_proj   = (const float*)d_in[6];
    const float* b_proj   = (const float*)d_in[7];
    const float* ln2_w    = (const float*)d_in[8];
    const float* ln2_b    = (const float*)d_in[9];
    const float* w_fc     = (const float*)d_in[10];
    const float* b_fc     = (const float*)d_in[11];
    const float* w_fcp    = (const float*)d_in[12];
    const float* b_fcp    = (const float*)d_in[13];
    float* out = (float*)d_out;

    ushort_t* ws = (ushort_t*)d_ws;
    ushort_t* qkvb   = ws;                               // BT*3*ND
    ushort_t* x1b    = qkvb + (size_t)BT * 3 * ND;       // BT*ND
    ushort_t* attn_b = x1b + (size_t)BT * ND;            // BT*ND
    ushort_t* hbuf   = attn_b + (size_t)BT * ND;         // BT*4*ND
    ushort_t* vTb    = hbuf + (size_t)BT * 4 * ND;       // BT*ND
    ushort_t* wA_T   = vTb + (size_t)BT * ND;            // 2304*768
    ushort_t* wP_T   = wA_T + (size_t)2304 * 768;        // 768*768
    ushort_t* wF_T   = wP_T + (size_t)768 * 768;         // 3072*768
    ushort_t* wFP_T  = wF_T + (size_t)3072 * 768;        // 768*3072

    static bool attr_set = false;
    if (!attr_set) {
        hipFuncSetAttribute((const void*)gemm256<0, 2304, 768>, hipFuncAttributeMaxDynamicSharedMemorySize, 131072);
        hipFuncSetAttribute((const void*)gemm256<2, 3072, 768>, hipFuncAttributeMaxDynamicSharedMemorySize, 131072);
        attr_set = true;
    }

    transpose_all<<<6912, 256, 0, stream>>>(w_attn, wA_T, w_proj, wP_T, w_fc, wF_T, w_fcp, wFP_T);

    ln_kernel<<<BT / 4, 256, 0, stream>>>(x, ln1_w, ln1_b, x1b);
    gemm256<0, 2304, 768><<<dim3(2304 / 256, BT / 256), 512, 131072, stream>>>(x1b, wA_T, b_attn, qkvb);
    transpose_v<<<dim3(16, NH, NB), 256, 0, stream>>>(qkvb, vTb);
    flash_attn_mfma<<<dim3(16, NH, NB), 256, 0, stream>>>(qkvb, vTb, amask, attn_b);
    gemm_bt<1><<<dim3(768 / 128, BT / 128), 256, 0, stream>>>(attn_b, wP_T, b_proj, x, out, BT, ND, ND);
    ln_kernel<<<BT / 4, 256, 0, stream>>>(out, ln2_w, ln2_b, x1b);
    gemm256<2, 3072, 768><<<dim3(3072 / 256, BT / 256), 512, 131072, stream>>>(x1b, wF_T, b_fc, hbuf);
    gemm_bt<1><<<dim3(768 / 128, BT / 128), 256, 0, stream>>>(hbuf, wFP_T, b_fcp, out, out, BT, ND, 4 * ND);
}

// Round 7
// 351.843 us; speedup vs baseline: 1.3076x; 1.0459x over previous
//
#include <hip/hip_runtime.h>
#include <hip/hip_bf16.h>
#include <math.h>

#define NB 8
#define NT 1024
#define ND 768
#define NH 12
#define HD 64
#define WINDOW 768
#define LN_EPS 1e-5f
#define NEGF -3.4028234663852886e38f
#define SCL2 0.18033688011112042f   // 0.125 * log2(e)

static const int BT = NB * NT;  // 8192 rows

typedef __bf16 bf16x8 __attribute__((ext_vector_type(8)));
typedef float  f32x4  __attribute__((ext_vector_type(4)));
typedef unsigned short ushort_t;

__device__ __forceinline__ unsigned short f2bf(float f) {
    __hip_bfloat16 h = __float2bfloat16(f);
    return __builtin_bit_cast(unsigned short, h);
}

// async global->LDS, 16B per lane. LDS dest = wave-uniform base + lane*16.
__device__ __forceinline__ void load_lds16(const void* g, void* l) {
    __builtin_amdgcn_global_load_lds((const __attribute__((address_space(1))) unsigned int*)g,
                                     (__attribute__((address_space(3))) unsigned int*)l,
                                     16, 0, 0);
}

// inline-asm ds_read_b128 with compile-time offset immediate: ONE base VGPR serves
// all fragment reads of a class (slot + subtile folded into offset:IMM).
template <int IMM>
__device__ __forceinline__ bf16x8 ds_read16o(unsigned base) {
    bf16x8 r;
    asm volatile("ds_read_b128 %0, %1 offset:%2" : "=v"(r) : "v"(base), "n"(IMM));
    return r;
}

// ---------------- all weight transposes fused: wT[n][k] = bf16(w[k][n]) --------
__global__ __launch_bounds__(256) void transpose_all(const float* __restrict__ w0, ushort_t* __restrict__ t0v,
                                                     const float* __restrict__ w1, ushort_t* __restrict__ t1v,
                                                     const float* __restrict__ w2, ushort_t* __restrict__ t2v,
                                                     const float* __restrict__ w3, ushort_t* __restrict__ t3v) {
    int bid = blockIdx.x;
    const float* w; ushort_t* wt; int K, N;
    if (bid < 1728)                    { w = w0; wt = t0v; K = 768;  N = 2304; }
    else if ((bid -= 1728) < 576)      { w = w1; wt = t1v; K = 768;  N = 768;  }
    else if ((bid -= 576) < 2304)      { w = w2; wt = t2v; K = 768;  N = 3072; }
    else       { bid -= 2304;            w = w3; wt = t3v; K = 3072; N = 768;  }
    const int nxt = N / 32;
    const int n0 = (bid % nxt) * 32, k0 = (bid / nxt) * 32;
    __shared__ float t[32][33];
    const int tx = threadIdx.x & 31, ty = threadIdx.x >> 5;  // 32 x 8
    for (int r = ty; r < 32; r += 8)
        t[r][tx] = w[(size_t)(k0 + r) * N + n0 + tx];
    __syncthreads();
    for (int r = ty; r < 32; r += 8)
        wt[(size_t)(n0 + r) * K + k0 + tx] = f2bf(t[tx][r]);
}

// ---------------- V transpose (pi-permuted keys): vT[b][h][d][t'] --------------
__global__ __launch_bounds__(256) void transpose_v(const ushort_t* __restrict__ qkvb,
                                                   ushort_t* __restrict__ vT) {
    const int t0 = blockIdx.x * 64;
    const int h = blockIdx.y, b = blockIdx.z;
    __shared__ ushort_t sm[64 * 72];
    const int tid = threadIdx.x;
    #pragma unroll
    for (int p = 0; p < 2; p++) {
        int idx = p * 256 + tid;
        int r = idx >> 3, c = idx & 7;
        *(bf16x8*)&sm[r * 72 + c * 8] =
            *(const bf16x8*)(qkvb + (size_t)(b * NT + t0 + r) * (3 * ND) + 2 * ND + h * HD + c * 8);
    }
    __syncthreads();
    #pragma unroll
    for (int p = 0; p < 2; p++) {
        int idx = p * 256 + tid;
        int d = idx >> 3, c2 = idx & 7;
        ushort_t tmp[8];
        #pragma unroll
        for (int j = 0; j < 8; j++) {
            int kp = c2 * 8 + j;
            int key = ((kp & 1) << 4) | ((kp >> 1) & 15) | (kp & 32);
            tmp[j] = sm[key * 72 + d];
        }
        *(bf16x8*)(vT + ((size_t)((b * NH + h) * HD + d)) * NT + t0 + c2 * 8) = *(bf16x8*)tmp;
    }
}

// ---------------- LayerNorm -> bf16: wave-per-row, shuffle reduce --------------
__global__ __launch_bounds__(256) void ln_kernel(const float* __restrict__ x,
                                                 const float* __restrict__ w,
                                                 const float* __restrict__ b,
                                                 ushort_t* __restrict__ out) {
    const int row  = blockIdx.x * 4 + (threadIdx.x >> 6);
    const int lane = threadIdx.x & 63;
    const float* xr = x + (size_t)row * ND;

    float4 v[3];
    #pragma unroll
    for (int s = 0; s < 3; s++) v[s] = *(const float4*)(xr + s * 256 + lane * 4);

    float sum = 0.f;
    #pragma unroll
    for (int s = 0; s < 3; s++) sum += v[s].x + v[s].y + v[s].z + v[s].w;
    #pragma unroll
    for (int off = 1; off < 64; off <<= 1) sum += __shfl_xor(sum, off, 64);
    const float mu = sum * (1.0f / ND);

    float var = 0.f;
    #pragma unroll
    for (int s = 0; s < 3; s++) {
        float a0 = v[s].x - mu, a1 = v[s].y - mu, a2 = v[s].z - mu, a3 = v[s].w - mu;
        var += a0 * a0 + a1 * a1 + a2 * a2 + a3 * a3;
    }
    #pragma unroll
    for (int off = 1; off < 64; off <<= 1) var += __shfl_xor(var, off, 64);
    const float rstd = rsqrtf(var * (1.0f / ND) + LN_EPS);

    #pragma unroll
    for (int s = 0; s < 3; s++) {
        const int col = s * 256 + lane * 4;
        float4 w4 = *(const float4*)(w + col);
        float4 b4 = *(const float4*)(b + col);
        ushort4 r;
        r.x = f2bf((v[s].x - mu) * rstd * w4.x + b4.x);
        r.y = f2bf((v[s].y - mu) * rstd * w4.y + b4.y);
        r.z = f2bf((v[s].z - mu) * rstd * w4.z + b4.z);
        r.w = f2bf((v[s].w - mu) * rstd * w4.w + b4.w);
        *(ushort4*)(out + (size_t)row * ND + col) = r;
    }
}

// ---------------- bf16 MFMA GEMM, double-buffered pipeline (128x128) -----------
// Kept for the two N=768 GEMMs, with bijective XCD-chunk swizzle (grids %8==0).
// EPI: 1 = +bias+resid -> fp32
template <int EPI>
__global__ __launch_bounds__(256) void gemm_bt(const ushort_t* __restrict__ A,
                                               const ushort_t* __restrict__ Bt,
                                               const float* __restrict__ bias,
                                               const float* __restrict__ resid,
                                               void* __restrict__ Cout,
                                               int M, int N, int K) {
    __shared__ __align__(16) ushort_t smem[2][2][128 * 32];  // [buf][A/B][...]

    const int tid  = threadIdx.x;
    const int nwg   = gridDim.x * gridDim.y;
    const int flatb = blockIdx.y * gridDim.x + blockIdx.x;
    const int q8    = nwg >> 3;
    const int swz   = (flatb & 7) * q8 + (flatb >> 3);
    const int bm   = (swz / gridDim.x) * 128;
    const int bn   = (swz % gridDim.x) * 128;
    const int lane = tid & 63;
    const int wave = tid >> 6;
    const int wm   = (wave & 1) * 64;
    const int wn   = (wave >> 1) * 64;
    const int fcol = lane & 15;
    const int quad = lane >> 4;

    f32x4 acc[4][4] = {};

    const int srow = tid >> 2, scg = (tid & 3) * 8;

    auto issue = [&](int k0, int buf) {
        #pragma unroll
        for (int p = 0; p < 2; p++) {
            const int row = srow + p * 64;
            const int flat = (p * 256 + tid) * 8;
            load_lds16(A  + (size_t)(bm + row) * K + k0 + scg, &smem[buf][0][flat]);
            load_lds16(Bt + (size_t)(bn + row) * K + k0 + scg, &smem[buf][1][flat]);
        }
    };

    issue(0, 0);
    const int KT = K >> 5;
    for (int kt = 0; kt < KT; kt++) {
        const int cur = kt & 1;
        __syncthreads();
        if (kt + 1 < KT) issue((kt + 1) << 5, cur ^ 1);

        bf16x8 a[4], b[4];
        #pragma unroll
        for (int i = 0; i < 4; i++)
            a[i] = *(const bf16x8*)&smem[cur][0][(wm + i * 16 + fcol) * 32 + quad * 8];
        #pragma unroll
        for (int j = 0; j < 4; j++)
            b[j] = *(const bf16x8*)&smem[cur][1][(wn + j * 16 + fcol) * 32 + quad * 8];
        #pragma unroll
        for (int i = 0; i < 4; i++)
            #pragma unroll
            for (int j = 0; j < 4; j++)
                acc[i][j] = __builtin_amdgcn_mfma_f32_16x16x32_bf16(a[i], b[j], acc[i][j], 0, 0, 0);
    }

    if (EPI == 1) {
        #pragma unroll
        for (int j = 0; j < 4; j++) {
            const int gcol = bn + wn + j * 16 + fcol;
            const float bs = bias[gcol];
            #pragma unroll
            for (int i = 0; i < 4; i++) {
                #pragma unroll
                for (int r = 0; r < 4; r++) {
                    const int grow = bm + wm + i * 16 + quad * 4 + r;
                    float val = acc[i][j][r] + bs + resid[(size_t)grow * N + gcol];
                    ((float*)Cout)[(size_t)grow * N + gcol] = val;
                }
            }
        }
    } else {
        __syncthreads();
        ushort_t* Cs = &smem[0][0][0] + wave * (64 * 40);
        #pragma unroll
        for (int hh = 0; hh < 2; hh++) {
            #pragma unroll
            for (int jj = 0; jj < 2; jj++) {
                const int j = hh * 2 + jj;
                const float bs = bias[bn + wn + j * 16 + fcol];
                #pragma unroll
                for (int i = 0; i < 4; i++) {
                    #pragma unroll
                    for (int r = 0; r < 4; r++) {
                        float val = acc[i][j][r] + bs;
                        if (EPI == 2) {
                            float y = 0.7978845608028654f * (val + 0.044715f * val * val * val);
                            float t = 1.0f - 2.0f / (1.0f + __expf(2.0f * y));
                            val = 0.5f * val * (1.0f + t);
                        }
                        const int lr = i * 16 + quad * 4 + r;
                        Cs[lr * 40 + jj * 16 + fcol] = f2bf(val);
                    }
                }
            }
            #pragma unroll
            for (int p = 0; p < 4; p++) {
                const int cid = p * 64 + lane;
                const int lr = cid >> 2, ck = cid & 3;
                bf16x8 vv = *(const bf16x8*)&Cs[lr * 40 + ck * 8];
                *(bf16x8*)((ushort_t*)Cout + (size_t)(bm + wm + lr) * N + bn + wn + hh * 32 + ck * 8) = vv;
            }
        }
    }
}

// ---------------- 128x256 BK=32 GEMM: counted-vmcnt + 2 blocks/CU --------------
// Residency-first geometry: 48 KB static LDS (2-slot A/B dbuf) + ~115 unified
// regs/wave (acc 64) -> 2 blocks/CU (16 waves), vs gemm256's 1 block (8 waves).
// Cross-block wave overlap (m114) hides the per-phase LGKM/VMW waits that the
// round-6 null-barrier A/B showed were NOT barrier-cost; grid fits residency
// (fc 768 blocks / 512 slots, qkv 576/512) killing the 2-round tail.
// Wait discipline (all session-verified patterns): inline-asm swizzled
// ds_read_b128 + LGKM(0)+sched_barrier; stage = exactly 3 global_load_lds
// (inverse-swizzled source, linear LDS dest); VMW(3) counted ledger:
//   prologue stage(0),stage(1) -> 6 outstanding, VMW(3) = tile0 landed.
//   iter t: read slot t&1; LGKM(0); MFMA; BARR (all waves done reading);
//           stage(t+2 -> slot t&1) [WAR-safe: after the barrier];
//           VMW(3) (6->3 = tile t+1 landed); BARR (publish). Tail stages clamp
//           kk to keep the 3-load ledger exact; epilogue full-drain before reuse.
// EPI: 0 = +bias -> bf16;  2 = +bias,gelu(tanh) -> bf16
template <int EPI, int NN, int KK>
__global__ __launch_bounds__(512, 4) void gemm128n(const ushort_t* __restrict__ A,
                                                   const ushort_t* __restrict__ Bt,
                                                   const float* __restrict__ bias,
                                                   ushort_t* __restrict__ Cout) {
    __shared__ __align__(16) ushort_t lds[24576];   // 48 KB: A 2x4096, B 2x8192 ushorts

    const int tid  = threadIdx.x;
    const int lane = tid & 63;
    const int wave = tid >> 6;     // 0..7
    const int wr   = wave >> 2;    // 0..1  (64-row half)
    const int wn   = wave & 3;     // 0..3  (64-col quarter)
    const int fcol = lane & 15;
    const int quad = lane >> 4;

    // bijective XCD-chunk swizzle (nwg = 576 / 768, both % 8 == 0)
    const int nwg   = gridDim.x * gridDim.y;
    const int flatb = blockIdx.y * gridDim.x + blockIdx.x;
    const int q8    = nwg >> 3;
    const int swz   = (flatb & 7) * q8 + (flatb >> 3);
    const int bm    = (swz / gridDim.x) * 128;
    const int bn    = (swz % gridDim.x) * 256;

    constexpr int KTILES = KK >> 5;   // 32-wide K tiles (24 for K=768)

    f32x4 acc[4][4] = {};             // 64 regs: wave's 64x64 output
    bf16x8 ra[4], rbv[4];

    // fragment-read bases; slot & subtile are offset: immediates.
    // in-slot layout: row r x 4 chunks of 16B, chunk stored at (c ^ (r&3));
    // frag rows == fcol (mod 4) so the XOR term is uniform per lane.
    const unsigned ldsb = (unsigned)(size_t)(const __attribute__((address_space(3))) ushort_t*)lds;
    const unsigned sw   = (unsigned)((quad ^ (fcol & 3)) * 16);
    const unsigned baseA = ldsb + (unsigned)((wr * 64 + fcol) * 64) + sw;
    const unsigned baseB = ldsb + 16384u + (unsigned)((wn * 64 + fcol) * 64) + sw;

    auto stage = [&](int kt) {   // exactly 3 global_load_lds per thread
        const int kk = (kt < KTILES ? kt : 0) << 5;   // clamp keeps vmcnt ledger
        ushort_t* dstA = lds + (kt & 1) * 4096;
        {
            const int f = tid;                         // 512 loads cover 128x32
            const int r = f >> 2, c = (f & 3) ^ (r & 3);
            load_lds16(A + (size_t)(bm + r) * KK + kk + c * 8, dstA + f * 8);
        }
        ushort_t* dstB = lds + 8192 + (kt & 1) * 8192;
        #pragma unroll
        for (int p = 0; p < 2; p++) {                  // 1024 loads cover 256x32
            const int f = (p << 9) + tid;
            const int r = f >> 2, c = (f & 3) ^ (r & 3);
            load_lds16(Bt + (size_t)(bn + r) * KK + kk + c * 8, dstB + f * 8);
        }
    };

#define RD_T(CUR) {                                                        \
    ra[0]  = ds_read16o<(CUR) * 8192 + 0   >(baseA);                       \
    ra[1]  = ds_read16o<(CUR) * 8192 + 1024>(baseA);                       \
    ra[2]  = ds_read16o<(CUR) * 8192 + 2048>(baseA);                       \
    ra[3]  = ds_read16o<(CUR) * 8192 + 3072>(baseA);                       \
    rbv[0] = ds_read16o<(CUR) * 16384 + 0   >(baseB);                      \
    rbv[1] = ds_read16o<(CUR) * 16384 + 1024>(baseB);                      \
    rbv[2] = ds_read16o<(CUR) * 16384 + 2048>(baseB);                      \
    rbv[3] = ds_read16o<(CUR) * 16384 + 3072>(baseB); }
#define LGKM0() { asm volatile("s_waitcnt lgkmcnt(0)" ::: "memory");       \
    __builtin_amdgcn_sched_barrier(0); }
#define MMA16() {                                                          \
    __builtin_amdgcn_s_setprio(1);                                         \
    _Pragma("unroll") for (int i = 0; i < 4; i++)                          \
    _Pragma("unroll") for (int j = 0; j < 4; j++)                          \
        acc[i][j] = __builtin_amdgcn_mfma_f32_16x16x32_bf16(               \
            ra[i], rbv[j], acc[i][j], 0, 0, 0);                            \
    __builtin_amdgcn_s_setprio(0);                                         \
    __builtin_amdgcn_sched_barrier(0); }
#define VMW3() asm volatile("s_waitcnt vmcnt(3)" ::: "memory")
#define BARR() asm volatile("s_barrier" ::: "memory")

    stage(0); stage(1);
    VMW3();                       // tile0's 3 oldest loads landed
    BARR();

    #pragma unroll 1
    for (int it = 0; it < KTILES / 2; ++it) {
        const int t = it << 1;
        // even tile -> slot 0
        RD_T(0);
        LGKM0();
        MMA16();
        BARR();                   // all waves done reading slot 0
        stage(t + 2);             // overwrite slot 0 (WAR-safe)
        VMW3();                   // tile t+1 landed (own-wave)
        BARR();                   // publish block-wide
        // odd tile -> slot 1
        RD_T(1);
        LGKM0();
        MMA16();
        BARR();
        stage(t + 3);
        VMW3();
        BARR();
    }

    // full drain before LDS reuse
    asm volatile("s_waitcnt vmcnt(0) lgkmcnt(0)" ::: "memory");
    BARR();

    // epilogue: per-wave 32-row LDS staging (32x72 per wave = 36 KB total)
    ushort_t* Cs = lds + wave * (32 * 72);
    #pragma unroll
    for (int h = 0; h < 2; h++) {
        #pragma unroll
        for (int j = 0; j < 4; j++) {
            const float bs = bias[bn + wn * 64 + j * 16 + fcol];
            #pragma unroll
            for (int i2 = 0; i2 < 2; i2++) {
                #pragma unroll
                for (int r = 0; r < 4; r++) {
                    float val = acc[h * 2 + i2][j][r] + bs;
                    if (EPI == 2) {
                        float y = 0.7978845608028654f * (val + 0.044715f * val * val * val);
                        float t = 1.0f - 2.0f / (1.0f + __expf(2.0f * y));
                        val = 0.5f * val * (1.0f + t);
                    }
                    Cs[(i2 * 16 + quad * 4 + r) * 72 + j * 16 + fcol] = f2bf(val);
                }
            }
        }
        __builtin_amdgcn_sched_barrier(0);   // order within-wave store->load
        #pragma unroll
        for (int p = 0; p < 4; p++) {
            const int cid = (p << 6) + lane;
            const int lr = cid >> 3, ck = cid & 7;
            bf16x8 vv = *(const bf16x8*)&Cs[lr * 72 + ck * 8];
            *(bf16x8*)(Cout + (size_t)(bm + wr * 64 + h * 32 + lr) * NN + bn + wn * 64 + ck * 8) = vv;
        }
        __builtin_amdgcn_sched_barrier(0);
    }
#undef RD_T
#undef LGKM0
#undef MMA16
#undef VMW3
#undef BARR
}

// ---------------- MFMA flash attention: no-max softmax, l via ones-MFMA --------
__global__ __launch_bounds__(256) void flash_attn_mfma(const ushort_t* __restrict__ qkvb,
                                                       const ushort_t* __restrict__ vT,
                                                       const int* __restrict__ amask,
                                                       ushort_t* __restrict__ out) {
    const int qt = 15 - blockIdx.x;   // heavy tiles first
    const int h  = blockIdx.y;
    const int b  = blockIdx.z;
    const int q0 = qt * 64;

    __shared__ __align__(16) ushort_t QPs[64 * 64];      // Q, then reused for P
    __shared__ __align__(16) ushort_t Ks[2][64 * 64];
    __shared__ __align__(16) ushort_t Vts[2][64 * 64];

    const int tid  = threadIdx.x;
    const int lane = tid & 63;
    const int wave = tid >> 6;
    const int fcol = lane & 15;
    const int quad = lane >> 4;
    const int wq0  = wave * 16;

    #pragma unroll
    for (int p = 0; p < 2; p++) {
        int flat = p * 256 + tid;
        int r = flat >> 3, c = (flat & 7) ^ (r & 7);
        load_lds16(qkvb + (size_t)(b * NT + q0 + r) * (3 * ND) + h * HD + c * 8, &QPs[flat * 8]);
    }
    __syncthreads();

    bf16x8 aQ[2];
    {
        const int qr = wq0 + fcol;
        #pragma unroll
        for (int ks = 0; ks < 2; ks++) {
            int c = ks * 4 + quad;
            aQ[ks] = *(const bf16x8*)&QPs[qr * 64 + ((c ^ (qr & 7)) * 8)];
        }
    }

    bf16x8 bones;
    #pragma unroll
    for (int i = 0; i < 8; i++) bones[i] = (__bf16)1.0f;

    auto issueKV = [&](int cch, int buf) {
        const int kbase = cch * 64;
        #pragma unroll
        for (int p = 0; p < 2; p++) {
            int flat = p * 256 + tid;
            int r = flat >> 3, c = (flat & 7) ^ (r & 7);
            load_lds16(qkvb + (size_t)(b * NT + kbase + r) * (3 * ND) + ND + h * HD + c * 8,
                       &Ks[buf][flat * 8]);
            load_lds16(vT + ((size_t)((b * NH + h) * HD + r)) * NT + kbase + c * 8,
                       &Vts[buf][flat * 8]);
        }
    };

    f32x4 oacc[4] = {};
    f32x4 lacc = {};

    const int c_lo = (qt > 12) ? (qt - 12) : 0;
    issueKV(c_lo, 0);
    for (int cch = c_lo; cch <= qt; cch++) {
        const int cur = (cch - c_lo) & 1;
        const int kbase = cch * 64;
        __syncthreads();
        if (cch + 1 <= qt) issueKV(cch + 1, cur ^ 1);

        int am[4];
        #pragma unroll
        for (int jn = 0; jn < 4; jn++) am[jn] = amask[b * NT + kbase + jn * 16 + fcol];
        const int amok_lane = (am[0] != 0) & (am[1] != 0) & (am[2] != 0) & (am[3] != 0);
        const bool fast = (cch < qt) && (cch >= qt - 11) && __all(amok_lane);

        f32x4 sc[4] = {};
        #pragma unroll
        for (int ks = 0; ks < 2; ks++) {
            #pragma unroll
            for (int jn = 0; jn < 4; jn++) {
                const int kr = jn * 16 + fcol;
                bf16x8 bk = *(const bf16x8*)&Ks[cur][kr * 64 + (((ks * 4 + quad) ^ (kr & 7)) * 8)];
                sc[jn] = __builtin_amdgcn_mfma_f32_16x16x32_bf16(aQ[ks], bk, sc[jn], 0, 0, 0);
            }
        }

        float pvv[4][4];
        if (fast) {
            #pragma unroll
            for (int jn = 0; jn < 4; jn++)
                #pragma unroll
                for (int r = 0; r < 4; r++)
                    pvv[jn][r] = __builtin_amdgcn_exp2f(sc[jn][r] * SCL2);
        } else {
            #pragma unroll
            for (int jn = 0; jn < 4; jn++) {
                const int jg = kbase + jn * 16 + fcol;
                const bool amok = (am[jn] != 0);
                #pragma unroll
                for (int r = 0; r < 4; r++) {
                    const int ig = q0 + wq0 + quad * 4 + r;
                    bool keep = (jg <= ig) && (jg >= ig - (WINDOW - 1)) && amok;
                    float s = keep ? sc[jn][r] * SCL2 : -1e38f;
                    pvv[jn][r] = __builtin_amdgcn_exp2f(s);
                }
            }
        }

        #pragma unroll
        for (int half = 0; half < 2; half++) {
            const int cbase = half * 4 + (fcol >> 2);
            const int off = (fcol & 3) * 2;
            #pragma unroll
            for (int r = 0; r < 4; r++) {
                const int row = wq0 + quad * 4 + r;
                unsigned int pk = (unsigned int)f2bf(pvv[half * 2][r]) |
                                  ((unsigned int)f2bf(pvv[half * 2 + 1][r]) << 16);
                *(unsigned int*)&QPs[row * 64 + ((cbase ^ (row & 7)) * 8) + off] = pk;
            }
        }

        #pragma unroll
        for (int ks = 0; ks < 2; ks++) {
            const int pr = wq0 + fcol;
            bf16x8 ap = *(const bf16x8*)&QPs[pr * 64 + (((ks * 4 + quad) ^ (pr & 7)) * 8)];
            lacc = __builtin_amdgcn_mfma_f32_16x16x32_bf16(ap, bones, lacc, 0, 0, 0);
            #pragma unroll
            for (int jd = 0; jd < 4; jd++) {
                const int vr = jd * 16 + fcol;
                bf16x8 bv = *(const bf16x8*)&Vts[cur][vr * 64 + (((ks * 4 + quad) ^ (vr & 7)) * 8)];
                oacc[jd] = __builtin_amdgcn_mfma_f32_16x16x32_bf16(ap, bv, oacc[jd], 0, 0, 0);
            }
        }
    }

    #pragma unroll
    for (int r = 0; r < 4; r++) {
        const float inv = 1.0f / lacc[r];
        const size_t row = (size_t)(b * NT + q0 + wq0 + quad * 4 + r);
        #pragma unroll
        for (int jd = 0; jd < 4; jd++)
            out[row * ND + h * HD + jd * 16 + fcol] = f2bf(oacc[jd][r] * inv);
    }
}

extern "C" void kernel_launch(void* const* d_in, const int* in_sizes, int n_in,
                              void* d_out, int out_size, void* d_ws, size_t ws_size,
                              hipStream_t stream) {
    const float* x        = (const float*)d_in[0];
    const int*   amask    = (const int*)  d_in[1];
    const float* ln1_w    = (const float*)d_in[2];
    const float* ln1_b    = (const float*)d_in[3];
    const float* w_attn   = (const float*)d_in[4];
    const float* b_attn   = (const float*)d_in[5];
    const float* w_proj   = (const float*)d_in[6];
    const float* b_proj   = (const float*)d_in[7];
    const float* ln2_w    = (const float*)d_in[8];
    const float* ln2_b    = (const float*)d_in[9];
    const float* w_fc     = (const float*)d_in[10];
    const float* b_fc     = (const float*)d_in[11];
    const float* w_fcp    = (const float*)d_in[12];
    const float* b_fcp    = (const float*)d_in[13];
    float* out = (float*)d_out;

    ushort_t* ws = (ushort_t*)d_ws;
    ushort_t* qkvb   = ws;                               // BT*3*ND
    ushort_t* x1b    = qkvb + (size_t)BT * 3 * ND;       // BT*ND
    ushort_t* attn_b = x1b + (size_t)BT * ND;            // BT*ND
    ushort_t* hbuf   = attn_b + (size_t)BT * ND;         // BT*4*ND
    ushort_t* vTb    = hbuf + (size_t)BT * 4 * ND;       // BT*ND
    ushort_t* wA_T   = vTb + (size_t)BT * ND;            // 2304*768
    ushort_t* wP_T   = wA_T + (size_t)2304 * 768;        // 768*768
    ushort_t* wF_T   = wP_T + (size_t)768 * 768;         // 3072*768
    ushort_t* wFP_T  = wF_T + (size_t)3072 * 768;        // 768*3072

    transpose_all<<<6912, 256, 0, stream>>>(w_attn, wA_T, w_proj, wP_T, w_fc, wF_T, w_fcp, wFP_T);

    ln_kernel<<<BT / 4, 256, 0, stream>>>(x, ln1_w, ln1_b, x1b);
    gemm128n<0, 2304, 768><<<dim3(2304 / 256, BT / 128), 512, 0, stream>>>(x1b, wA_T, b_attn, qkvb);
    transpose_v<<<dim3(16, NH, NB), 256, 0, stream>>>(qkvb, vTb);
    flash_attn_mfma<<<dim3(16, NH, NB), 256, 0, stream>>>(qkvb, vTb, amask, attn_b);
    gemm_bt<1><<<dim3(768 / 128, BT / 128), 256, 0, stream>>>(attn_b, wP_T, b_proj, x, out, BT, ND, ND);
    ln_kernel<<<BT / 4, 256, 0, stream>>>(out, ln2_w, ln2_b, x1b);
    gemm128n<2, 3072, 768><<<dim3(3072 / 256, BT / 128), 512, 0, stream>>>(x1b, wF_T, b_fc, hbuf);
    gemm_bt<1><<<dim3(768 / 128, BT / 128), 256, 0, stream>>>(hbuf, wFP_T, b_fcp, out, out, BT, ND, 4 * ND);
}